// Round 11
// baseline (2906.139 us; speedup 1.0000x reference)
//
#include <hip/hip_runtime.h>
#include <cstdint>
#include <cstddef>

typedef __attribute__((ext_vector_type(8))) short short8;
typedef __attribute__((ext_vector_type(4))) float f32x4;
typedef __attribute__((ext_vector_type(4))) unsigned int uint4v;

#define DEV static __device__ __forceinline__

DEV float b2f(unsigned short u){ union{unsigned int i; float f;} v; v.i = ((unsigned int)u)<<16; return v.f; }
DEV unsigned short f2b(float f){
  union{float f; unsigned int i;} v; v.f = f;
  unsigned int u = v.i;
  unsigned int r = (u + 0x7fffu + ((u>>16)&1u)) >> 16;
  return (unsigned short)r;
}
DEV float sigm(float x){ return 1.0f/(1.0f + __expf(-x)); }
DEV float tanhfast(float x){ return 1.0f - 2.0f/(1.0f + __expf(2.0f*x)); }

// device-coherent (bypass L1/L2, complete at IF$) 16B load
DEV uint4v ld_sc_b128(const unsigned short* p){
  uint4v d;
  asm volatile("global_load_dwordx4 %0, %1, off sc0 sc1" : "=v"(d) : "v"(p) : "memory");
  return d;
}
// f32 row -> bf16x8 fragment
DEV short8 ldw8(const float* p){
  short8 w;
  #pragma unroll
  for (int e = 0; e < 8; ++e) w[e] = (short)f2b(p[e]);
  return w;
}

// ---------------- prep kernels ----------------
__global__ __launch_bounds__(256) void k_cast(const float* __restrict__ s, unsigned short* __restrict__ d, int n){
  int i = blockIdx.x*256 + threadIdx.x;
  if (i < n) d[i] = f2b(s[i]);
}
__global__ __launch_bounds__(256) void k_transpose_enc(const float* __restrict__ enc, unsigned short* __restrict__ encT){
  int i = blockIdx.x*256 + threadIdx.x;   // over 16*512*512, out index [b][h][s]
  if (i >= 16*512*512) return;
  int b = i >> 18, r = i & 262143, h = r >> 9, s = r & 511;
  encT[i] = f2b(enc[(b<<18) + (s<<9) + h]);
}
__global__ __launch_bounds__(256) void k_gather(const int* __restrict__ trg, const float* __restrict__ emb, unsigned short* __restrict__ X){
  int i = blockIdx.x*256 + threadIdx.x;   // over 8192*512, row = t*16+b
  if (i >= 8192*512) return;
  int r = i >> 9, e = i & 511;
  int t = r >> 4, b = r & 15;
  int tok = trg[(b<<9) + t];
  X[i] = f2b(emb[((size_t)tok<<9) + e]);
}
__global__ __launch_bounds__(256) void k_bsum(const float* __restrict__ bi, const float* __restrict__ bh, float* __restrict__ o){
  int i = blockIdx.x*256 + threadIdx.x;
  if (i < 8192) o[i] = bi[i] + bh[i];
}
__global__ __launch_bounds__(256) void k_init(const float* __restrict__ h0, unsigned short* __restrict__ Hst0,
                                              unsigned short* __restrict__ Hst1, unsigned int* __restrict__ bar){
  int i = blockIdx.x*256 + threadIdx.x;
  if (i < 256) bar[i] = 0;            // flags: l0 d0/d1 @0/32, l1 d0/d1 @64/96
  if (i < 16384) {                    // buf0 region: [dir][b][k] ; h0 flat [l*2+dir][b][k]
    Hst0[i] = f2b(h0[i]);             // layer 0: dirs 0,1
    Hst1[i] = f2b(h0[16384 + i]);     // layer 1: dirs 2,3
  }
}
// enc_proj f32 -> ENC3 [b*512+s][1536] = [hi | lo | hi]
__global__ __launch_bounds__(256) void k_split(const float* __restrict__ S, unsigned short* __restrict__ E3, int n){
  int i = blockIdx.x*256 + threadIdx.x;
  if (i >= n) return;
  int r = i >> 9, j = i & 511;
  float f = S[i];
  unsigned short hi = f2b(f);
  unsigned short lo = f2b(f - b2f(hi));
  size_t base = (size_t)r * 1536 + j;
  E3[base] = hi;
  E3[base + 512] = lo;
  E3[base + 1024] = hi;
}
// dec = hf+hb -> DCTX[:, :512] bf16 ; DEC3 [t*16+b][1536] = [hi | hi | lo]
__global__ __launch_bounds__(256) void k_decsplit(const float* __restrict__ HF, unsigned short* __restrict__ DCTX,
                                                  unsigned short* __restrict__ D3){
  int i = blockIdx.x*256 + threadIdx.x;  // 8192*512
  if (i >= 8192*512) return;
  int r = i >> 9, j = i & 511;
  float d = HF[((size_t)r<<10) + j] + HF[((size_t)r<<10) + 512 + j];
  unsigned short hi = f2b(d);
  unsigned short lo = f2b(d - b2f(hi));
  DCTX[((size_t)r<<10) + j] = hi;
  size_t base = (size_t)r * 1536 + j;
  D3[base] = hi;
  D3[base + 512] = hi;
  D3[base + 1024] = lo;
}

// ---------------- generic bf16 MFMA GEMM: C = A[M,K] @ W[N,K]^T (+bias) ----------------
// MODE: 0 = store bf16, 1 = store f32 (+bias), 2 = FC epilogue (mask+remap)
template<int MODE>
__global__ __launch_bounds__(256) void k_gemm(
    const unsigned short* __restrict__ A, long lda, long sA,
    const unsigned short* __restrict__ W, long ldw, long sW,
    void* __restrict__ C, long ldc, long sC,
    const float* __restrict__ bias,
    int M, int N, int K,
    const int* __restrict__ tlen)
{
  __shared__ short8 AsV[128*5];   // 128 rows x 32 bf16, padded stride 5x short8 (conflict-spread)
  __shared__ short8 WsV[128*5];
  const int bz = blockIdx.z;
  const unsigned short* Ab = A + (size_t)bz * sA;
  const unsigned short* Wb = W + (size_t)bz * sW;
  const int m0 = blockIdx.x << 7, n0 = blockIdx.y << 7;
  const int tid = threadIdx.x;
  const int wave = tid >> 6, lane = tid & 63;
  const int ln = lane & 15, kq = lane >> 4;
  const int wm = wave >> 1, wn = wave & 1;
  const int ar0 = tid >> 2, ac0 = (tid & 3) << 3;
  const int ar1 = ar0 + 64;
  const short8 z8 = {0,0,0,0,0,0,0,0};

  f32x4 acc[4][4];
  #pragma unroll
  for (int i = 0; i < 4; ++i)
    #pragma unroll
    for (int j = 0; j < 4; ++j) { f32x4 z = {0.f,0.f,0.f,0.f}; acc[i][j] = z; }

  for (int k0 = 0; k0 < K; k0 += 32) {
    short8 a0 = *(const short8*)(Ab + (size_t)(m0+ar0)*lda + k0 + ac0);
    short8 a1 = *(const short8*)(Ab + (size_t)(m0+ar1)*lda + k0 + ac0);
    short8 w0 = z8, w1 = z8;
    if (MODE != 2 || (n0+ar0) < N) w0 = *(const short8*)(Wb + (size_t)(n0+ar0)*ldw + k0 + ac0);
    if (MODE != 2 || (n0+ar1) < N) w1 = *(const short8*)(Wb + (size_t)(n0+ar1)*ldw + k0 + ac0);
    __syncthreads();
    AsV[ar0*5 + (ac0>>3)] = a0;
    AsV[ar1*5 + (ac0>>3)] = a1;
    WsV[ar0*5 + (ac0>>3)] = w0;
    WsV[ar1*5 + (ac0>>3)] = w1;
    __syncthreads();
    short8 af[4], wf[4];
    #pragma unroll
    for (int i = 0; i < 4; ++i) af[i] = AsV[((wm<<6) + (i<<4) + ln)*5 + kq];
    #pragma unroll
    for (int i = 0; i < 4; ++i) wf[i] = WsV[((wn<<6) + (i<<4) + ln)*5 + kq];
    #pragma unroll
    for (int i = 0; i < 4; ++i)
      #pragma unroll
      for (int j = 0; j < 4; ++j)
        acc[i][j] = __builtin_amdgcn_mfma_f32_16x16x32_bf16(af[i], wf[j], acc[i][j], 0, 0, 0);
  }
  #pragma unroll
  for (int j = 0; j < 4; ++j) {
    const int n = n0 + (wn<<6) + (j<<4) + ln;
    float bi = 0.f;
    if (MODE == 0 || MODE == 1) { if (bias) bi = bias[n]; }
    if (MODE == 2) { if (n < N) bi = bias[n]; }
    #pragma unroll
    for (int i = 0; i < 4; ++i) {
      #pragma unroll
      for (int r = 0; r < 4; ++r) {
        const int m = m0 + (wm<<6) + (i<<4) + (kq<<2) + r;
        float v = acc[i][j][r] + bi;
        if (MODE == 0) ((unsigned short*)C)[(size_t)bz*sC + (size_t)m*ldc + n] = f2b(v);
        else if (MODE == 1) ((float*)C)[(size_t)bz*sC + (size_t)m*ldc + n] = v;
        else {
          if (n < N) {
            int tt = m >> 4, bb = m & 15;
            ((float*)C)[((size_t)((bb<<9) + tt))*1000 + n] = (tt < tlen[bb]) ? v : 0.0f;
          }
        }
      }
    }
  }
}

// ---------------- fused 2-layer persistent LSTM (wave-specialized, 128x512) ----------------
// blocks 0-63: layer 0 (waves 0-3 compute; waves 4-7 help staging only).
// blocks 64-127: layer 1: waves 0-3 = critical h-chain (poll->h1 stage->16 MFMA->
//   cell->store->flag); waves 4-7 = x-pipeline (stage h0cat(t+1) in parallel with
//   h1 stage; 32 x-MFMAs into double-buffered gshX during the cell/store phase).
// All cross-block data via sc0sc1 (IF$-coherent); flags on packed 128B lines;
// no fences anywhere (W/Xg stay cached).
__global__ __launch_bounds__(512, 1) void k_recur(
    const float* __restrict__ whh,            // [2 layer][2 dir][2048][512] f32
    const float* __restrict__ wih1,           // [2 dir][2048][1024] f32
    const unsigned short* __restrict__ Xg0,   // [8192][4096] bf16 (l0: x@Wih0^T + biases)
    const float* __restrict__ c0all,          // [4][16][512] f32
    const float* __restrict__ bsum,           // [8192] f32 (b_ih+b_hh)
    unsigned short* __restrict__ Hst0,        // [2 buf][2 dir][16][512] bf16
    unsigned short* __restrict__ Hst1,        // [2 buf][2 dir][16][512] bf16
    unsigned short* __restrict__ Hcat,        // [8192][1024] bf16 (l0 output)
    float* __restrict__ HcatF,                // [8192][1024] f32  (l1 output)
    unsigned int* __restrict__ flags)
{
  const int bid = blockIdx.x;
  const int dir = (bid >> 5) & 1;
  const int j0  = (bid & 31) << 4;
  const int tid = threadIdx.x;
  const int wave = tid >> 6, lane = tid & 63;
  const int ln = lane & 15, kq = lane >> 4;
  const int b_ = (tid & 255) >> 4, jl = tid & 15;
  const int myfl = bid & 31, pollfl = lane & 31;

  __shared__ __align__(16) unsigned char h0sh[32768];   // l1: h0cat tile [16][1024]
  __shared__ __align__(16) unsigned char h1sh[16384];   // own-h tile [16][512]
  __shared__ float gsh[4][16][16];
  __shared__ float gshX[2][4][16][16];

  unsigned int* FL0d0 = flags;
  unsigned int* FL0d1 = flags + 32;

  if (bid < 64) {
    // ================= layer 0 =================
    unsigned int* FL = flags + (dir << 5);
    short8 wfrag[16];
    if (wave < 4) {
      const float* wb = whh + (((size_t)((dir<<11) + (wave<<9) + j0 + ln)) << 9) + (kq<<3);
      #pragma unroll
      for (int ks = 0; ks < 16; ++ks) wfrag[ks] = ldw8(wb + (ks<<5));
    }
    float c = 0.f, xg0 = 0.f, xg1 = 0.f, xg2 = 0.f, xg3 = 0.f;
    if (tid < 256) {
      c = c0all[(((size_t)((dir<<4) + b_)) << 9) + j0 + jl];
      size_t xr = ((size_t)b_ << 12) + (dir<<11) + j0 + jl;
      xg0 = b2f(Xg0[xr]);
      xg1 = b2f(Xg0[xr + 512]);
      xg2 = b2f(Xg0[xr + 1024]);
      xg3 = b2f(Xg0[xr + 1536]);
    }

    for (int t = 0; t < 512; ++t) {
      // stage h(t): 16KB, 512 threads x 2 dwordx4
      const unsigned short* hbase = Hst0 + ((((t&1)<<1) + dir)<<13);
      uint4v st[2];
      #pragma unroll
      for (int cc = 0; cc < 2; ++cc)
        st[cc] = ld_sc_b128(hbase + (cc<<12) + (tid<<3));
      asm volatile("s_waitcnt vmcnt(0)" ::: "memory");
      #pragma unroll
      for (int cc = 0; cc < 2; ++cc) {
        int g = (cc<<9) + tid, row = g >> 6, slot = g & 63, ps = slot ^ row;
        *(uint4v*)(h1sh + row*1024 + (ps<<4)) = st[cc];
      }
      __syncthreads();   // (A)

      if (tid < 256) {
        f32x4 acc0 = {0.f,0.f,0.f,0.f}, acc1 = {0.f,0.f,0.f,0.f};
        #pragma unroll
        for (int ks = 0; ks < 16; ks += 2) {
          short8 a0 = *(const short8*)(h1sh + ln*1024 + ((((ks<<2)+kq) ^ ln)<<4));
          short8 a1 = *(const short8*)(h1sh + ln*1024 + (((((ks+1)<<2)+kq) ^ ln)<<4));
          acc0 = __builtin_amdgcn_mfma_f32_16x16x32_bf16(a0, wfrag[ks],   acc0, 0, 0, 0);
          acc1 = __builtin_amdgcn_mfma_f32_16x16x32_bf16(a1, wfrag[ks+1], acc1, 0, 0, 0);
        }
        f32x4 acc = acc0 + acc1;
        #pragma unroll
        for (int r = 0; r < 4; ++r)
          gsh[wave][(kq<<2)+r][ln] = acc[r];
      }
      __syncthreads();   // (B)

      if (tid < 256) {
        float gi = gsh[0][b_][jl] + xg0;
        float gf = gsh[1][b_][jl] + xg1;
        float gg = gsh[2][b_][jl] + xg2;
        float go = gsh[3][b_][jl] + xg3;
        float ii = sigm(gi), ff = sigm(gf);
        float g2 = tanhfast(gg), oo = sigm(go);
        c = ff*c + ii*g2;
        float h = oo * tanhfast(c);
        unsigned short h16 = f2b(h);

        unsigned int hu = (unsigned int)h16;
        unsigned int hv1 = __shfl_down(hu, 1);
        unsigned int hv2 = __shfl_down(hu, 2);
        unsigned int hv3 = __shfl_down(hu, 3);
        if (!(lane & 3)) {
          unsigned long long hq = (unsigned long long)(hu | (hv1 << 16))
                                | ((unsigned long long)(hv2 | (hv3 << 16)) << 32);
          unsigned short* dst = Hst0 + (((((t+1)&1)<<1) + dir)<<13) + (b_<<9) + j0 + jl;
          __hip_atomic_store((unsigned long long*)dst, hq, __ATOMIC_RELAXED, __HIP_MEMORY_SCOPE_AGENT);
          unsigned short* dc = Hcat + (((size_t)((t<<4) + b_))<<10) + (dir<<9) + j0 + jl;
          __hip_atomic_store((unsigned long long*)dc, hq, __ATOMIC_RELAXED, __HIP_MEMORY_SCOPE_AGENT);
        }

        if (t < 511) {
          size_t xr = (((size_t)(((t+1)<<4) + b_)) << 12) + (dir<<11) + j0 + jl;
          xg0 = b2f(Xg0[xr]);
          xg1 = b2f(Xg0[xr + 512]);
          xg2 = b2f(Xg0[xr + 1024]);
          xg3 = b2f(Xg0[xr + 1536]);
        }
      }

      __syncthreads();   // (C) vmcnt(0): sc stores acked at IF$
      if (tid == 0)
        __hip_atomic_store(FL + myfl, (unsigned int)(t + 1), __ATOMIC_RELAXED, __HIP_MEMORY_SCOPE_AGENT);
      if (t == 511) break;

      if (wave == 0) {
        const unsigned int tgt = (unsigned int)(t + 1);
        while (!__all((int)(__hip_atomic_load(FL + pollfl, __ATOMIC_RELAXED, __HIP_MEMORY_SCOPE_AGENT) >= tgt)))
          __builtin_amdgcn_s_sleep(1);
      }
      __syncthreads();   // (D)
    }
  } else {
    // ================= layer 1 (wave-specialized) =================
    unsigned int* FL = flags + 64 + (dir << 5);
    const int xq = (wave >= 4) ? (wave - 4) : 0;
    const int xtid = tid & 255;
    short8 whf[16];
    short8 wxf[32];
    if (wave < 4) {
      const float* wb = whh + 2097152 + (((size_t)((dir<<11) + (wave<<9) + j0 + ln)) << 9) + (kq<<3);
      #pragma unroll
      for (int ks = 0; ks < 16; ++ks) whf[ks] = ldw8(wb + (ks<<5));
    } else {
      const float* xb = wih1 + (((size_t)((dir<<11) + (xq<<9) + j0 + ln)) << 10) + (kq<<3);
      #pragma unroll
      for (int ks = 0; ks < 32; ++ks) wxf[ks] = ldw8(xb + (ks<<5));
    }
    float c = 0.f, bs0 = 0.f, bs1 = 0.f, bs2 = 0.f, bs3 = 0.f;
    if (tid < 256) {
      c = c0all[16384 + (((size_t)((dir<<4) + b_)) << 9) + j0 + jl];
      bs0 = bsum[4096 + (dir<<11) + 0*512 + j0 + jl];
      bs1 = bsum[4096 + (dir<<11) + 1*512 + j0 + jl];
      bs2 = bsum[4096 + (dir<<11) + 2*512 + j0 + jl];
      bs3 = bsum[4096 + (dir<<11) + 3*512 + j0 + jl];
    }

    // prologue: wave4 waits l0 (both dirs) >= 1 -> h0cat(0) ready
    if (wave == 4) {
      const unsigned int* fp = (lane < 32) ? (FL0d0 + lane) : (FL0d1 + (lane - 32));
      while (!__all((int)(__hip_atomic_load(fp, __ATOMIC_RELAXED, __HIP_MEMORY_SCOPE_AGENT) >= 1u)))
        __builtin_amdgcn_s_sleep(1);
    }
    __syncthreads();   // (P1)
    if (wave >= 4) {   // stage h0cat(0)
      uint4v sx[8];
      #pragma unroll
      for (int cc = 0; cc < 8; ++cc) {
        int g = (cc<<8) + xtid, row = g >> 7, slot = g & 127;
        sx[cc] = ld_sc_b128(Hcat + (row<<10) + (slot<<3));
      }
      asm volatile("s_waitcnt vmcnt(0)" ::: "memory");
      #pragma unroll
      for (int cc = 0; cc < 8; ++cc) {
        int g = (cc<<8) + xtid, row = g >> 7, slot = g & 127, ps = slot ^ row;
        *(uint4v*)(h0sh + row*2048 + (ps<<4)) = sx[cc];
      }
    }
    __syncthreads();   // (P2)
    if (wave >= 4) {   // x-gates(0) -> gshX[0]
      f32x4 xa = {0.f,0.f,0.f,0.f}, xb2 = {0.f,0.f,0.f,0.f};
      #pragma unroll
      for (int ks = 0; ks < 32; ks += 2) {
        short8 a0 = *(const short8*)(h0sh + ln*2048 + ((((ks<<2)+kq) ^ ln)<<4));
        short8 a1 = *(const short8*)(h0sh + ln*2048 + (((((ks+1)<<2)+kq) ^ ln)<<4));
        xa  = __builtin_amdgcn_mfma_f32_16x16x32_bf16(a0, wxf[ks],   xa, 0, 0, 0);
        xb2 = __builtin_amdgcn_mfma_f32_16x16x32_bf16(a1, wxf[ks+1], xb2, 0, 0, 0);
      }
      f32x4 x = xa + xb2;
      #pragma unroll
      for (int r = 0; r < 4; ++r)
        gshX[0][xq][(kq<<2)+r][ln] = x[r];
    }

    for (int t = 0; t < 512; ++t) {
      // pre-D polls
      if (wave == 0) {
        if (t > 0) {
          const unsigned int tgt = (unsigned int)t;
          while (!__all((int)(__hip_atomic_load(FL + pollfl, __ATOMIC_RELAXED, __HIP_MEMORY_SCOPE_AGENT) >= tgt)))
            __builtin_amdgcn_s_sleep(1);
        }
      } else if (wave == 4) {
        const unsigned int tgt = (t + 2 < 512) ? (unsigned int)(t + 2) : 512u;  // h0cat(t+1)
        const unsigned int* fp = (lane < 32) ? (FL0d0 + lane) : (FL0d1 + (lane - 32));
        while (!__all((int)(__hip_atomic_load(fp, __ATOMIC_RELAXED, __HIP_MEMORY_SCOPE_AGENT) >= tgt)))
          __builtin_amdgcn_s_sleep(1);
      }
      __syncthreads();   // (D)

      if (wave < 4) {
        // stage h1(t): 16KB by 256 threads
        const unsigned short* h1base = Hst1 + ((((t&1)<<1) + dir)<<13);
        uint4v sh[4];
        #pragma unroll
        for (int cc = 0; cc < 4; ++cc)
          sh[cc] = ld_sc_b128(h1base + (cc<<11) + (tid<<3));
        asm volatile("s_waitcnt vmcnt(0)" ::: "memory");
        #pragma unroll
        for (int cc = 0; cc < 4; ++cc) {
          int g = (cc<<8) + tid, row = g >> 6, slot = g & 63, ps = slot ^ row;
          *(uint4v*)(h1sh + row*1024 + (ps<<4)) = sh[cc];
        }
      } else if (t < 511) {
        // stage h0cat(t+1): 32KB by 256 threads (parallel with h1 stage)
        const unsigned short* h0base = Hcat + (((size_t)(t+1)) << 14);
        uint4v sx[8];
        #pragma unroll
        for (int cc = 0; cc < 8; ++cc) {
          int g = (cc<<8) + xtid, row = g >> 7, slot = g & 127;
          sx[cc] = ld_sc_b128(h0base + (row<<10) + (slot<<3));
        }
        asm volatile("s_waitcnt vmcnt(0)" ::: "memory");
        #pragma unroll
        for (int cc = 0; cc < 8; ++cc) {
          int g = (cc<<8) + xtid, row = g >> 7, slot = g & 127, ps = slot ^ row;
          *(uint4v*)(h0sh + row*2048 + (ps<<4)) = sx[cc];
        }
      }
      __syncthreads();   // (A)

      if (wave < 4) {
        f32x4 acc0 = {0.f,0.f,0.f,0.f}, acc1 = {0.f,0.f,0.f,0.f};
        #pragma unroll
        for (int ks = 0; ks < 16; ks += 2) {
          short8 a0 = *(const short8*)(h1sh + ln*1024 + ((((ks<<2)+kq) ^ ln)<<4));
          short8 a1 = *(const short8*)(h1sh + ln*1024 + (((((ks+1)<<2)+kq) ^ ln)<<4));
          acc0 = __builtin_amdgcn_mfma_f32_16x16x32_bf16(a0, whf[ks],   acc0, 0, 0, 0);
          acc1 = __builtin_amdgcn_mfma_f32_16x16x32_bf16(a1, whf[ks+1], acc1, 0, 0, 0);
        }
        f32x4 acc = acc0 + acc1;
        #pragma unroll
        for (int r = 0; r < 4; ++r)
          gsh[wave][(kq<<2)+r][ln] = acc[r];
      }
      __syncthreads();   // (B)

      if (tid < 256) {
        float gi = gsh[0][b_][jl] + gshX[t&1][0][b_][jl] + bs0;
        float gf = gsh[1][b_][jl] + gshX[t&1][1][b_][jl] + bs1;
        float gg = gsh[2][b_][jl] + gshX[t&1][2][b_][jl] + bs2;
        float go = gsh[3][b_][jl] + gshX[t&1][3][b_][jl] + bs3;
        float ii = sigm(gi), ff = sigm(gf);
        float g2 = tanhfast(gg), oo = sigm(go);
        c = ff*c + ii*g2;
        float h = oo * tanhfast(c);
        unsigned short h16 = f2b(h);

        unsigned int hu = (unsigned int)h16;
        unsigned int hv1 = __shfl_down(hu, 1);
        unsigned int hv2 = __shfl_down(hu, 2);
        unsigned int hv3 = __shfl_down(hu, 3);
        if (!(lane & 3)) {
          unsigned long long hq = (unsigned long long)(hu | (hv1 << 16))
                                | ((unsigned long long)(hv2 | (hv3 << 16)) << 32);
          unsigned short* dst = Hst1 + (((((t+1)&1)<<1) + dir)<<13) + (b_<<9) + j0 + jl;
          __hip_atomic_store((unsigned long long*)dst, hq, __ATOMIC_RELAXED, __HIP_MEMORY_SCOPE_AGENT);
        }
        __builtin_nontemporal_store(h, HcatF + (((size_t)((t<<4) + b_))<<10) + (dir<<9) + j0 + jl);
      } else if (t < 511) {
        // x-gates(t+1) -> gshX[(t+1)&1]   (overlaps cell/store phase)
        f32x4 xa = {0.f,0.f,0.f,0.f}, xb2 = {0.f,0.f,0.f,0.f};
        #pragma unroll
        for (int ks = 0; ks < 32; ks += 2) {
          short8 a0 = *(const short8*)(h0sh + ln*2048 + ((((ks<<2)+kq) ^ ln)<<4));
          short8 a1 = *(const short8*)(h0sh + ln*2048 + (((((ks+1)<<2)+kq) ^ ln)<<4));
          xa  = __builtin_amdgcn_mfma_f32_16x16x32_bf16(a0, wxf[ks],   xa, 0, 0, 0);
          xb2 = __builtin_amdgcn_mfma_f32_16x16x32_bf16(a1, wxf[ks+1], xb2, 0, 0, 0);
        }
        f32x4 x = xa + xb2;
        #pragma unroll
        for (int r = 0; r < 4; ++r)
          gshX[(t+1)&1][xq][(kq<<2)+r][ln] = x[r];
      }

      __syncthreads();   // (C) vmcnt(0): sc store acked
      if (tid == 0)
        __hip_atomic_store(FL + myfl, (unsigned int)(t + 1), __ATOMIC_RELAXED, __HIP_MEMORY_SCOPE_AGENT);
    }
  }
}

// ---------------- softmax over masked scores -> bf16 attention ----------------
__global__ __launch_bounds__(256) void k_softmax(const float* __restrict__ score, const int* __restrict__ tlen,
                                                 unsigned short* __restrict__ att){
  int row = (blockIdx.x<<2) + (threadIdx.x>>6);   // row = b*512 + t
  int lane = threadIdx.x & 63;
  int b = row >> 9;
  int len = tlen[b];
  const float* sr = score + ((size_t)row<<9);
  float v[8]; float m = -3.0e38f;
  #pragma unroll
  for (int i = 0; i < 8; ++i) {
    int s = (i<<6) + lane;
    float x = sr[s];
    v[i] = (s < len) ? x : -1.0e30f;
    m = fmaxf(m, v[i]);
  }
  #pragma unroll
  for (int off = 32; off; off >>= 1) m = fmaxf(m, __shfl_xor(m, off));
  float sum = 0.f; float p[8];
  #pragma unroll
  for (int i = 0; i < 8; ++i) { p[i] = __expf(v[i] - m); sum += p[i]; }
  #pragma unroll
  for (int off = 32; off; off >>= 1) sum += __shfl_xor(sum, off);
  float inv = 1.0f / sum;
  unsigned short* ar = att + ((size_t)row<<9);
  #pragma unroll
  for (int i = 0; i < 8; ++i) ar[(i<<6) + lane] = f2b(p[i]*inv);
}

// ---------------- host ----------------
extern "C" void kernel_launch(void* const* d_in, const int* in_sizes, int n_in,
                              void* d_out, int out_size, void* d_ws, size_t ws_size,
                              hipStream_t stream) {
  (void)in_sizes; (void)n_in; (void)out_size; (void)ws_size;
  const int*   trg  = (const int*)d_in[0];
  const int*   tlen = (const int*)d_in[1];
  const float* enc  = (const float*)d_in[2];
  const float* h0   = (const float*)d_in[3];
  const float* c0   = (const float*)d_in[4];
  const float* emb  = (const float*)d_in[5];
  const float* wih0 = (const float*)d_in[6];
  const float* wih1 = (const float*)d_in[7];
  const float* whh  = (const float*)d_in[8];
  const float* bih  = (const float*)d_in[9];
  const float* bhh  = (const float*)d_in[10];
  const float* watt = (const float*)d_in[11];
  const float* batt = (const float*)d_in[12];
  const float* wfc  = (const float*)d_in[13];
  const float* bfc  = (const float*)d_in[14];
  float* out = (float*)d_out;

  char* ws = (char*)d_ws;
  size_t off = 0;
  auto alloc = [&](size_t bytes)->char* {
    char* p = ws + off; off += (bytes + 255) & ~(size_t)255; return p;
  };
  unsigned int*   BAR   = (unsigned int*)  alloc(1024);    // flag lines
  unsigned short* XEMB  = (unsigned short*)alloc(8192ll*512*2);
  unsigned short* WI0B  = (unsigned short*)alloc(4096ll*512*2);
  unsigned short* WFCB  = (unsigned short*)alloc(1000ll*1024*2);
  unsigned short* WATTB = (unsigned short*)alloc(512ll*512*2);
  unsigned short* ENCB  = (unsigned short*)alloc(8192ll*512*2);
  unsigned short* ENCT  = (unsigned short*)alloc(8192ll*512*2);
  float*          BSUM  = (float*)         alloc(8192*4);
  unsigned short* HST0  = (unsigned short*)alloc(32768*2);
  unsigned short* HST1  = (unsigned short*)alloc(32768*2);
  unsigned short* XG    = (unsigned short*)alloc(8192ll*4096*2);
  unsigned short* HCAT  = (unsigned short*)alloc(8192ll*1024*2);
  float*          HCATF = (float*)         alloc(8192ll*1024*4);
  float*          SCORE = (float*)         alloc(8192ll*512*4);   // enc_proj staging, then scores
  unsigned short* ATT   = (unsigned short*)alloc(8192ll*512*2);
  unsigned short* DCTX  = (unsigned short*)alloc(8192ll*1024*2);
  // DEC3/ENC3 alias XG (dead after k_recur): [8192][1536] each
  unsigned short* DEC3  = XG;
  unsigned short* ENC3  = XG + 8192ll*1536;

  auto cdiv = [](long a, long b){ return (int)((a + b - 1) / b); };

  // ---- prep ----
  k_cast<<<cdiv(2097152,256),256,0,stream>>>(wih0, WI0B, 2097152);
  k_cast<<<cdiv(1024000,256),256,0,stream>>>(wfc,  WFCB, 1024000);
  k_cast<<<cdiv(262144,256),256,0,stream>>>(watt, WATTB, 262144);
  k_cast<<<cdiv(4194304,256),256,0,stream>>>(enc,  ENCB, 4194304);
  k_transpose_enc<<<cdiv(4194304,256),256,0,stream>>>(enc, ENCT);
  k_gather<<<cdiv(4194304,256),256,0,stream>>>(trg, emb, XEMB);
  k_bsum<<<cdiv(8192,256),256,0,stream>>>(bih, bhh, BSUM);
  k_init<<<cdiv(32768,256),256,0,stream>>>(h0, HST0, HST1, BAR);

  // ---- enc_proj = enc @ W_att^T + b_att (f32) ----
  k_gemm<1><<<dim3(64,4,1),256,0,stream>>>(ENCB,512,0, WATTB,512,0, (void*)SCORE,512,0, batt, 8192,512,512, nullptr);

  // ---- X0 = Xemb @ W_ih0^T + (b_ih+b_hh)[0]  -> XG bf16 ----
  k_gemm<0><<<dim3(64,32,1),256,0,stream>>>(XEMB,512,0, WI0B,512,0, (void*)XG,4096,0, BSUM, 8192,4096,512, nullptr);

  // ---- fused pipelined 2-layer recurrence (wave-specialized) ----
  k_recur<<<128,512,0,stream>>>(whh, wih1, XG, c0, BSUM, HST0, HST1, HCAT, HCATF, BAR);

  // ---- ENC3 (hi|lo|hi) from enc_proj; DEC3 (hi|hi|lo) + DCTX dec half ----
  k_split<<<cdiv(4194304,256),256,0,stream>>>(SCORE, ENC3, 4194304);
  k_decsplit<<<cdiv(4194304,256),256,0,stream>>>(HCATF, DCTX, DEC3);

  // ---- score: single K=1536 compensated GEMM (batched z=b) ----
  k_gemm<1><<<dim3(4,4,16),256,0,stream>>>(DEC3,24576,1536, ENC3,1536,786432, (void*)SCORE,512,262144, nullptr, 512,512,1536, nullptr);

  // ---- masked softmax -> ATT bf16 ----
  k_softmax<<<2048,256,0,stream>>>(SCORE, tlen, ATT);

  // ---- ctx[b,t,h] = att @ enc  -> DCTX[:, 512:] bf16 (batched) ----
  k_gemm<0><<<dim3(4,4,16),256,0,stream>>>(ATT,512,262144, ENCT,512,262144, (void*)(DCTX+512),16384,1024, nullptr, 512,512,512, nullptr);

  // ---- out = [dec,ctx] @ W_fc^T + b_fc, masked by trg_len ----
  k_gemm<2><<<dim3(64,8,1),256,0,stream>>>(DCTX,1024,0, WFCB,1024,0, (void*)out,1000,0, bfc, 8192,1000,1024, tlen);
}

// Round 13
// 1937.916 us; speedup vs baseline: 1.4996x; 1.4996x over previous
//
#include <hip/hip_runtime.h>
#include <cstdint>
#include <cstddef>

typedef __attribute__((ext_vector_type(8))) short short8;
typedef __attribute__((ext_vector_type(4))) float f32x4;
typedef __attribute__((ext_vector_type(4))) unsigned int uint4v;

#define DEV static __device__ __forceinline__

DEV float b2f(unsigned short u){ union{unsigned int i; float f;} v; v.i = ((unsigned int)u)<<16; return v.f; }
DEV unsigned short f2b(float f){
  union{float f; unsigned int i;} v; v.f = f;
  unsigned int u = v.i;
  unsigned int r = (u + 0x7fffu + ((u>>16)&1u)) >> 16;
  return (unsigned short)r;
}
DEV float sigm(float x){ return 1.0f/(1.0f + __expf(-x)); }
DEV float tanhfast(float x){ return 1.0f - 2.0f/(1.0f + __expf(2.0f*x)); }

// device-coherent (bypass L1/L2, complete at IF$) 16B load — proven primitive (r7+)
DEV uint4v ld_sc_b128(const unsigned short* p){
  uint4v d;
  asm volatile("global_load_dwordx4 %0, %1, off sc0 sc1" : "=v"(d) : "v"(p) : "memory");
  return d;
}
// f32 row -> bf16x8 fragment
DEV short8 ldw8(const float* p){
  short8 w;
  #pragma unroll
  for (int e = 0; e < 8; ++e) w[e] = (short)f2b(p[e]);
  return w;
}

// ---------------- prep kernels ----------------
__global__ __launch_bounds__(256) void k_cast(const float* __restrict__ s, unsigned short* __restrict__ d, int n){
  int i = blockIdx.x*256 + threadIdx.x;
  if (i < n) d[i] = f2b(s[i]);
}
__global__ __launch_bounds__(256) void k_transpose_enc(const float* __restrict__ enc, unsigned short* __restrict__ encT){
  int i = blockIdx.x*256 + threadIdx.x;   // over 16*512*512, out index [b][h][s]
  if (i >= 16*512*512) return;
  int b = i >> 18, r = i & 262143, h = r >> 9, s = r & 511;
  encT[i] = f2b(enc[(b<<18) + (s<<9) + h]);
}
__global__ __launch_bounds__(256) void k_gather(const int* __restrict__ trg, const float* __restrict__ emb, unsigned short* __restrict__ X){
  int i = blockIdx.x*256 + threadIdx.x;   // over 8192*512, row = t*16+b
  if (i >= 8192*512) return;
  int r = i >> 9, e = i & 511;
  int t = r >> 4, b = r & 15;
  int tok = trg[(b<<9) + t];
  X[i] = f2b(emb[((size_t)tok<<9) + e]);
}
__global__ __launch_bounds__(256) void k_bsum(const float* __restrict__ bi, const float* __restrict__ bh, float* __restrict__ o){
  int i = blockIdx.x*256 + threadIdx.x;
  if (i < 8192) o[i] = bi[i] + bh[i];
}
__global__ __launch_bounds__(256) void k_init(const float* __restrict__ h0, unsigned short* __restrict__ Hst0,
                                              unsigned short* __restrict__ Hst1, unsigned int* __restrict__ bar){
  int i = blockIdx.x*256 + threadIdx.x;
  if (i < 256) bar[i] = 0;            // flags: l0 d0/d1 @0/32, l1 d0/d1 @64/96, xp d0/d1 @128/160
  if (i < 16384) {                    // buf0 region: [dir][b][k] ; h0 flat [l*2+dir][b][k]
    Hst0[i] = f2b(h0[i]);             // layer 0: dirs 0,1
    Hst1[i] = f2b(h0[16384 + i]);     // layer 1: dirs 2,3
  }
}
// enc_proj f32 -> ENC3 [b*512+s][1536] = [hi | lo | hi]
__global__ __launch_bounds__(256) void k_split(const float* __restrict__ S, unsigned short* __restrict__ E3, int n){
  int i = blockIdx.x*256 + threadIdx.x;
  if (i >= n) return;
  int r = i >> 9, j = i & 511;
  float f = S[i];
  unsigned short hi = f2b(f);
  unsigned short lo = f2b(f - b2f(hi));
  size_t base = (size_t)r * 1536 + j;
  E3[base] = hi;
  E3[base + 512] = lo;
  E3[base + 1024] = hi;
}
// dec = hf+hb -> DCTX[:, :512] bf16 ; DEC3 [t*16+b][1536] = [hi | hi | lo]
__global__ __launch_bounds__(256) void k_decsplit(const float* __restrict__ HF, unsigned short* __restrict__ DCTX,
                                                  unsigned short* __restrict__ D3){
  int i = blockIdx.x*256 + threadIdx.x;  // 8192*512
  if (i >= 8192*512) return;
  int r = i >> 9, j = i & 511;
  float d = HF[((size_t)r<<10) + j] + HF[((size_t)r<<10) + 512 + j];
  unsigned short hi = f2b(d);
  unsigned short lo = f2b(d - b2f(hi));
  DCTX[((size_t)r<<10) + j] = hi;
  size_t base = (size_t)r * 1536 + j;
  D3[base] = hi;
  D3[base + 512] = hi;
  D3[base + 1024] = lo;
}

// ---------------- generic bf16 MFMA GEMM: C = A[M,K] @ W[N,K]^T (+bias) ----------------
// MODE: 0 = store bf16, 1 = store f32 (+bias), 2 = FC epilogue (mask+remap)
template<int MODE>
__global__ __launch_bounds__(256) void k_gemm(
    const unsigned short* __restrict__ A, long lda, long sA,
    const unsigned short* __restrict__ W, long ldw, long sW,
    void* __restrict__ C, long ldc, long sC,
    const float* __restrict__ bias,
    int M, int N, int K,
    const int* __restrict__ tlen)
{
  __shared__ short8 AsV[128*5];   // 128 rows x 32 bf16, padded stride 5x short8 (conflict-spread)
  __shared__ short8 WsV[128*5];
  const int bz = blockIdx.z;
  const unsigned short* Ab = A + (size_t)bz * sA;
  const unsigned short* Wb = W + (size_t)bz * sW;
  const int m0 = blockIdx.x << 7, n0 = blockIdx.y << 7;
  const int tid = threadIdx.x;
  const int wave = tid >> 6, lane = tid & 63;
  const int ln = lane & 15, kq = lane >> 4;
  const int wm = wave >> 1, wn = wave & 1;
  const int ar0 = tid >> 2, ac0 = (tid & 3) << 3;
  const int ar1 = ar0 + 64;
  const short8 z8 = {0,0,0,0,0,0,0,0};

  f32x4 acc[4][4];
  #pragma unroll
  for (int i = 0; i < 4; ++i)
    #pragma unroll
    for (int j = 0; j < 4; ++j) { f32x4 z = {0.f,0.f,0.f,0.f}; acc[i][j] = z; }

  for (int k0 = 0; k0 < K; k0 += 32) {
    short8 a0 = *(const short8*)(Ab + (size_t)(m0+ar0)*lda + k0 + ac0);
    short8 a1 = *(const short8*)(Ab + (size_t)(m0+ar1)*lda + k0 + ac0);
    short8 w0 = z8, w1 = z8;
    if (MODE != 2 || (n0+ar0) < N) w0 = *(const short8*)(Wb + (size_t)(n0+ar0)*ldw + k0 + ac0);
    if (MODE != 2 || (n0+ar1) < N) w1 = *(const short8*)(Wb + (size_t)(n0+ar1)*ldw + k0 + ac0);
    __syncthreads();
    AsV[ar0*5 + (ac0>>3)] = a0;
    AsV[ar1*5 + (ac0>>3)] = a1;
    WsV[ar0*5 + (ac0>>3)] = w0;
    WsV[ar1*5 + (ac0>>3)] = w1;
    __syncthreads();
    short8 af[4], wf[4];
    #pragma unroll
    for (int i = 0; i < 4; ++i) af[i] = AsV[((wm<<6) + (i<<4) + ln)*5 + kq];
    #pragma unroll
    for (int i = 0; i < 4; ++i) wf[i] = WsV[((wn<<6) + (i<<4) + ln)*5 + kq];
    #pragma unroll
    for (int i = 0; i < 4; ++i)
      #pragma unroll
      for (int j = 0; j < 4; ++j)
        acc[i][j] = __builtin_amdgcn_mfma_f32_16x16x32_bf16(af[i], wf[j], acc[i][j], 0, 0, 0);
  }
  #pragma unroll
  for (int j = 0; j < 4; ++j) {
    const int n = n0 + (wn<<6) + (j<<4) + ln;
    float bi = 0.f;
    if (MODE == 0 || MODE == 1) { if (bias) bi = bias[n]; }
    if (MODE == 2) { if (n < N) bi = bias[n]; }
    #pragma unroll
    for (int i = 0; i < 4; ++i) {
      #pragma unroll
      for (int r = 0; r < 4; ++r) {
        const int m = m0 + (wm<<6) + (i<<4) + (kq<<2) + r;
        float v = acc[i][j][r] + bi;
        if (MODE == 0) ((unsigned short*)C)[(size_t)bz*sC + (size_t)m*ldc + n] = f2b(v);
        else if (MODE == 1) ((float*)C)[(size_t)bz*sC + (size_t)m*ldc + n] = v;
        else {
          if (n < N) {
            int tt = m >> 4, bb = m & 15;
            ((float*)C)[((size_t)((bb<<9) + tt))*1000 + n] = (tt < tlen[bb]) ? v : 0.0f;
          }
        }
      }
    }
  }
}

// ---------------- fused 2-layer persistent LSTM (producer/consumer, 192x256) ----------------
// blocks 0-63:    layer 0 (r10-proven structure), publishes Hst0 + Hcat + flags[0..63].
// blocks 128-191: x-producers: per step poll l0(t+1) -> stage h0cat(t) 32KB ->
//                 32 MFMAs (W_ih1 in regs) -> two packed 8B ATOMIC stores per thread
//                 into 8-deep ring XG1 -> flag[128..191]. Ring overwrite guarded
//                 by polling consumer flags >= t-7.
// blocks 64-127:  l1 consumers: poll own flags(t) + producer flags(t+1) ->
//                 stage h1 16KB + ONE 16B xg sc load -> 16 MFMAs -> cell ->
//                 store -> flag[64..127]. Chain structurally identical to l0.
// All cross-block publishes use __hip_atomic_store (proven correct flags);
// sc loads for staging; no fences anywhere.
__global__ __launch_bounds__(256, 1) void k_recur(
    const float* __restrict__ whh,            // [2 layer][2 dir][2048][512] f32
    const float* __restrict__ wih1,           // [2 dir][2048][1024] f32
    const unsigned short* __restrict__ Xg0,   // [8192][4096] bf16 (l0: x@Wih0^T + biases)
    const float* __restrict__ c0all,          // [4][16][512] f32
    const float* __restrict__ bsum,           // [8192] f32 (b_ih+b_hh)
    unsigned short* __restrict__ Hst0,        // [2 buf][2 dir][16][512] bf16
    unsigned short* __restrict__ Hst1,        // [2 buf][2 dir][16][512] bf16
    unsigned short* __restrict__ Hcat,        // [8192][1024] bf16 (l0 output)
    float* __restrict__ HcatF,                // [8192][1024] f32  (l1 output)
    float* __restrict__ XG1,                  // [8 slot][2 dir][16 b][512 j][4 g] f32 ring
    unsigned int* __restrict__ flags)
{
  const int bid = blockIdx.x;
  const int dir = (bid >> 5) & 1;
  const int j0  = (bid & 31) << 4;
  const int tid = threadIdx.x;
  const int wave = tid >> 6, lane = tid & 63;
  const int ln = lane & 15, kq = lane >> 4;
  const int b_ = tid >> 4, jl = tid & 15;
  const int myfl = bid & 31, pollfl = lane & 31;

  __shared__ __align__(16) unsigned char h0sh[32768];   // producer: h0cat tile [16][1024]
  __shared__ __align__(16) unsigned char h1sh[16384];   // l0/l1: own-h tile [16][512]
  __shared__ float gsh[4][16][16];

  unsigned int* FL0d0 = flags;
  unsigned int* FL0d1 = flags + 32;

  if (bid < 64) {
    // ================= layer 0 =================
    unsigned int* FL = flags + (dir << 5);
    short8 wfrag[16];
    {
      const float* wb = whh + (((size_t)((dir<<11) + (wave<<9) + j0 + ln)) << 9) + (kq<<3);
      #pragma unroll
      for (int ks = 0; ks < 16; ++ks) wfrag[ks] = ldw8(wb + (ks<<5));
    }
    float c = c0all[(((size_t)((dir<<4) + b_)) << 9) + j0 + jl];

    size_t xr = ((size_t)b_ << 12) + (dir<<11) + j0 + jl;
    float xg0 = b2f(Xg0[xr]);
    float xg1 = b2f(Xg0[xr + 512]);
    float xg2 = b2f(Xg0[xr + 1024]);
    float xg3 = b2f(Xg0[xr + 1536]);

    for (int t = 0; t < 512; ++t) {
      const unsigned short* hbase = Hst0 + ((((t&1)<<1) + dir)<<13);
      uint4v st[4];
      #pragma unroll
      for (int cc = 0; cc < 4; ++cc)
        st[cc] = ld_sc_b128(hbase + (cc<<11) + (tid<<3));
      asm volatile("s_waitcnt vmcnt(0)" ::: "memory");
      #pragma unroll
      for (int cc = 0; cc < 4; ++cc) {
        int g = (cc<<8) + tid, row = g >> 6, slot = g & 63, ps = slot ^ row;
        *(uint4v*)(h1sh + row*1024 + (ps<<4)) = st[cc];
      }
      __syncthreads();

      f32x4 acc0 = {0.f,0.f,0.f,0.f}, acc1 = {0.f,0.f,0.f,0.f};
      #pragma unroll
      for (int ks = 0; ks < 16; ks += 2) {
        short8 a0 = *(const short8*)(h1sh + ln*1024 + ((((ks<<2)+kq) ^ ln)<<4));
        short8 a1 = *(const short8*)(h1sh + ln*1024 + (((((ks+1)<<2)+kq) ^ ln)<<4));
        acc0 = __builtin_amdgcn_mfma_f32_16x16x32_bf16(a0, wfrag[ks],   acc0, 0, 0, 0);
        acc1 = __builtin_amdgcn_mfma_f32_16x16x32_bf16(a1, wfrag[ks+1], acc1, 0, 0, 0);
      }
      f32x4 acc = acc0 + acc1;
      #pragma unroll
      for (int r = 0; r < 4; ++r)
        gsh[wave][(kq<<2)+r][ln] = acc[r];
      __syncthreads();

      float gi = gsh[0][b_][jl] + xg0;
      float gf = gsh[1][b_][jl] + xg1;
      float gg = gsh[2][b_][jl] + xg2;
      float go = gsh[3][b_][jl] + xg3;
      float ii = sigm(gi), ff = sigm(gf);
      float g2 = tanhfast(gg), oo = sigm(go);
      c = ff*c + ii*g2;
      float h = oo * tanhfast(c);
      unsigned short h16 = f2b(h);

      // packed 8B sc stores: Hst0 next buf + Hcat (both published by the flag)
      unsigned int hu = (unsigned int)h16;
      unsigned int hv1 = __shfl_down(hu, 1);
      unsigned int hv2 = __shfl_down(hu, 2);
      unsigned int hv3 = __shfl_down(hu, 3);
      if (!(lane & 3)) {
        unsigned long long hq = (unsigned long long)(hu | (hv1 << 16))
                              | ((unsigned long long)(hv2 | (hv3 << 16)) << 32);
        unsigned short* dst = Hst0 + (((((t+1)&1)<<1) + dir)<<13) + (b_<<9) + j0 + jl;
        __hip_atomic_store((unsigned long long*)dst, hq, __ATOMIC_RELAXED, __HIP_MEMORY_SCOPE_AGENT);
        unsigned short* dc = Hcat + (((size_t)((t<<4) + b_))<<10) + (dir<<9) + j0 + jl;
        __hip_atomic_store((unsigned long long*)dc, hq, __ATOMIC_RELAXED, __HIP_MEMORY_SCOPE_AGENT);
      }

      // prefetch Xg for t+1 (plain cached; hides under the barrier)
      if (t < 511) {
        xr = (((size_t)(((t+1)<<4) + b_)) << 12) + (dir<<11) + j0 + jl;
        xg0 = b2f(Xg0[xr]);
        xg1 = b2f(Xg0[xr + 512]);
        xg2 = b2f(Xg0[xr + 1024]);
        xg3 = b2f(Xg0[xr + 1536]);
      }

      __syncthreads();   // vmcnt(0): sc stores acked at IF$
      if (tid == 0)
        __hip_atomic_store(FL + myfl, (unsigned int)(t + 1), __ATOMIC_RELAXED, __HIP_MEMORY_SCOPE_AGENT);
      if (t == 511) break;

      if (wave == 0) {
        const unsigned int tgt = (unsigned int)(t + 1);
        while (!__all((int)(__hip_atomic_load(FL + pollfl, __ATOMIC_RELAXED, __HIP_MEMORY_SCOPE_AGENT) >= tgt)))
          __builtin_amdgcn_s_sleep(1);
      }
      __syncthreads();
    }
  } else if (bid < 128) {
    // ================= layer 1 consumer =================
    unsigned int* FL  = flags + 64 + (dir << 5);
    unsigned int* FXP = flags + 128 + (dir << 5);
    short8 whf[16];
    {
      const float* wb = whh + 2097152 + (((size_t)((dir<<11) + (wave<<9) + j0 + ln)) << 9) + (kq<<3);
      #pragma unroll
      for (int ks = 0; ks < 16; ++ks) whf[ks] = ldw8(wb + (ks<<5));
    }
    float c = c0all[16384 + (((size_t)((dir<<4) + b_)) << 9) + j0 + jl];
    float bs0 = bsum[4096 + (dir<<11) + 0*512 + j0 + jl];
    float bs1 = bsum[4096 + (dir<<11) + 1*512 + j0 + jl];
    float bs2 = bsum[4096 + (dir<<11) + 2*512 + j0 + jl];
    float bs3 = bsum[4096 + (dir<<11) + 3*512 + j0 + jl];

    for (int t = 0; t < 512; ++t) {
      // pre-D polls: own-dir h1(t) ready; xg(t) published by producer
      if (wave == 0) {
        if (t > 0) {
          const unsigned int tgt = (unsigned int)t;
          while (!__all((int)(__hip_atomic_load(FL + pollfl, __ATOMIC_RELAXED, __HIP_MEMORY_SCOPE_AGENT) >= tgt)))
            __builtin_amdgcn_s_sleep(1);
        }
      } else if (wave == 1) {
        const unsigned int tgt = (unsigned int)(t + 1);
        while (!__all((int)(__hip_atomic_load(FXP + pollfl, __ATOMIC_RELAXED, __HIP_MEMORY_SCOPE_AGENT) >= tgt)))
          __builtin_amdgcn_s_sleep(1);
      }
      __syncthreads();   // (D)

      // stage h1(t) 16KB + issue xg 16B load (single vmcnt window)
      const unsigned short* h1base = Hst1 + ((((t&1)<<1) + dir)<<13);
      uint4v sh[4];
      #pragma unroll
      for (int cc = 0; cc < 4; ++cc)
        sh[cc] = ld_sc_b128(h1base + (cc<<11) + (tid<<3));
      const float* xp = XG1 + ((((size_t)((((t&7)<<1) + dir)<<4) + b_)<<9) + j0 + jl)*4;
      uint4v xgu = ld_sc_b128((const unsigned short*)xp);
      asm volatile("s_waitcnt vmcnt(0)" ::: "memory");
      #pragma unroll
      for (int cc = 0; cc < 4; ++cc) {
        int g = (cc<<8) + tid, row = g >> 6, slot = g & 63, ps = slot ^ row;
        *(uint4v*)(h1sh + row*1024 + (ps<<4)) = sh[cc];
      }
      __syncthreads();   // (A)

      f32x4 acc0 = {0.f,0.f,0.f,0.f}, acc1 = {0.f,0.f,0.f,0.f};
      #pragma unroll
      for (int ks = 0; ks < 16; ks += 2) {
        short8 a0 = *(const short8*)(h1sh + ln*1024 + ((((ks<<2)+kq) ^ ln)<<4));
        short8 a1 = *(const short8*)(h1sh + ln*1024 + (((((ks+1)<<2)+kq) ^ ln)<<4));
        acc0 = __builtin_amdgcn_mfma_f32_16x16x32_bf16(a0, whf[ks],   acc0, 0, 0, 0);
        acc1 = __builtin_amdgcn_mfma_f32_16x16x32_bf16(a1, whf[ks+1], acc1, 0, 0, 0);
      }
      f32x4 acc = acc0 + acc1;
      #pragma unroll
      for (int r = 0; r < 4; ++r)
        gsh[wave][(kq<<2)+r][ln] = acc[r];
      __syncthreads();   // (B)

      union { uint4v u; f32x4 f; } xg; xg.u = xgu;
      float gi = gsh[0][b_][jl] + xg.f[0] + bs0;
      float gf = gsh[1][b_][jl] + xg.f[1] + bs1;
      float gg = gsh[2][b_][jl] + xg.f[2] + bs2;
      float go = gsh[3][b_][jl] + xg.f[3] + bs3;
      float ii = sigm(gi), ff = sigm(gf);
      float g2 = tanhfast(gg), oo = sigm(go);
      c = ff*c + ii*g2;
      float h = oo * tanhfast(c);
      unsigned short h16 = f2b(h);

      unsigned int hu = (unsigned int)h16;
      unsigned int hv1 = __shfl_down(hu, 1);
      unsigned int hv2 = __shfl_down(hu, 2);
      unsigned int hv3 = __shfl_down(hu, 3);
      if (!(lane & 3)) {
        unsigned long long hq = (unsigned long long)(hu | (hv1 << 16))
                              | ((unsigned long long)(hv2 | (hv3 << 16)) << 32);
        unsigned short* dst = Hst1 + (((((t+1)&1)<<1) + dir)<<13) + (b_<<9) + j0 + jl;
        __hip_atomic_store((unsigned long long*)dst, hq, __ATOMIC_RELAXED, __HIP_MEMORY_SCOPE_AGENT);
      }
      __builtin_nontemporal_store(h, HcatF + (((size_t)((t<<4) + b_))<<10) + (dir<<9) + j0 + jl);

      __syncthreads();   // (C) vmcnt(0): sc store acked
      if (tid == 0)
        __hip_atomic_store(FL + myfl, (unsigned int)(t + 1), __ATOMIC_RELAXED, __HIP_MEMORY_SCOPE_AGENT);
    }
  } else {
    // ================= x-producer =================
    unsigned int* FXP = flags + 128 + (dir << 5);
    unsigned int* FL1 = flags + 64  + (dir << 5);
    short8 wxf[32];   // wave = gate q
    {
      const float* xb = wih1 + (((size_t)((dir<<11) + (wave<<9) + j0 + ln)) << 10) + (kq<<3);
      #pragma unroll
      for (int ks = 0; ks < 32; ++ks) wxf[ks] = ldw8(xb + (ks<<5));
    }

    for (int t = 0; t < 512; ++t) {
      // polls: l0 (both dirs) >= t+1 -> h0cat(t) ready; consumers >= t-7 -> slot free
      if (wave == 0) {
        const unsigned int tgt = (unsigned int)(t + 1);
        const unsigned int* fp = (lane < 32) ? (FL0d0 + lane) : (FL0d1 + (lane - 32));
        while (!__all((int)(__hip_atomic_load(fp, __ATOMIC_RELAXED, __HIP_MEMORY_SCOPE_AGENT) >= tgt)))
          __builtin_amdgcn_s_sleep(1);
      } else if (wave == 1 && t >= 8) {
        const unsigned int tgt = (unsigned int)(t - 7);
        while (!__all((int)(__hip_atomic_load(FL1 + pollfl, __ATOMIC_RELAXED, __HIP_MEMORY_SCOPE_AGENT) >= tgt)))
          __builtin_amdgcn_s_sleep(1);
      }
      __syncthreads();

      // stage h0cat(t): 32KB sc
      const unsigned short* h0base = Hcat + (((size_t)t) << 14);
      uint4v sx[8];
      #pragma unroll
      for (int cc = 0; cc < 8; ++cc) {
        int g = (cc<<8) + tid, row = g >> 7, slot = g & 127;
        sx[cc] = ld_sc_b128(h0base + (row<<10) + (slot<<3));
      }
      asm volatile("s_waitcnt vmcnt(0)" ::: "memory");
      #pragma unroll
      for (int cc = 0; cc < 8; ++cc) {
        int g = (cc<<8) + tid, row = g >> 7, slot = g & 127, ps = slot ^ row;
        *(uint4v*)(h0sh + row*2048 + (ps<<4)) = sx[cc];
      }
      __syncthreads();

      // 32 MFMAs: x-gate partial sums for gate q = wave
      f32x4 xa = {0.f,0.f,0.f,0.f}, xb2 = {0.f,0.f,0.f,0.f};
      #pragma unroll
      for (int ks = 0; ks < 32; ks += 2) {
        short8 a0 = *(const short8*)(h0sh + ln*2048 + ((((ks<<2)+kq) ^ ln)<<4));
        short8 a1 = *(const short8*)(h0sh + ln*2048 + (((((ks+1)<<2)+kq) ^ ln)<<4));
        xa  = __builtin_amdgcn_mfma_f32_16x16x32_bf16(a0, wxf[ks],   xa, 0, 0, 0);
        xb2 = __builtin_amdgcn_mfma_f32_16x16x32_bf16(a1, wxf[ks+1], xb2, 0, 0, 0);
      }
      f32x4 x = xa + xb2;
      #pragma unroll
      for (int r = 0; r < 4; ++r)
        gsh[wave][(kq<<2)+r][ln] = x[r];
      __syncthreads();

      // pack 4 gates -> TWO 8B ATOMIC stores into ring slot t&7 (proven publish primitive)
      {
        union { f32x4 f; unsigned long long u[2]; } xg;
        xg.f[0] = gsh[0][b_][jl];
        xg.f[1] = gsh[1][b_][jl];
        xg.f[2] = gsh[2][b_][jl];
        xg.f[3] = gsh[3][b_][jl];
        float* dst = XG1 + ((((size_t)((((t&7)<<1) + dir)<<4) + b_)<<9) + j0 + jl)*4;
        __hip_atomic_store((unsigned long long*)dst,       xg.u[0], __ATOMIC_RELAXED, __HIP_MEMORY_SCOPE_AGENT);
        __hip_atomic_store(((unsigned long long*)dst) + 1, xg.u[1], __ATOMIC_RELAXED, __HIP_MEMORY_SCOPE_AGENT);
      }

      __syncthreads();   // vmcnt(0): stores acked + gsh reads done
      if (tid == 0)
        __hip_atomic_store(FXP + myfl, (unsigned int)(t + 1), __ATOMIC_RELAXED, __HIP_MEMORY_SCOPE_AGENT);
    }
  }
}

// ---------------- softmax over masked scores -> bf16 attention ----------------
__global__ __launch_bounds__(256) void k_softmax(const float* __restrict__ score, const int* __restrict__ tlen,
                                                 unsigned short* __restrict__ att){
  int row = (blockIdx.x<<2) + (threadIdx.x>>6);   // row = b*512 + t
  int lane = threadIdx.x & 63;
  int b = row >> 9;
  int len = tlen[b];
  const float* sr = score + ((size_t)row<<9);
  float v[8]; float m = -3.0e38f;
  #pragma unroll
  for (int i = 0; i < 8; ++i) {
    int s = (i<<6) + lane;
    float x = sr[s];
    v[i] = (s < len) ? x : -1.0e30f;
    m = fmaxf(m, v[i]);
  }
  #pragma unroll
  for (int off = 32; off; off >>= 1) m = fmaxf(m, __shfl_xor(m, off));
  float sum = 0.f; float p[8];
  #pragma unroll
  for (int i = 0; i < 8; ++i) { p[i] = __expf(v[i] - m); sum += p[i]; }
  #pragma unroll
  for (int off = 32; off; off >>= 1) sum += __shfl_xor(sum, off);
  float inv = 1.0f / sum;
  unsigned short* ar = att + ((size_t)row<<9);
  #pragma unroll
  for (int i = 0; i < 8; ++i) ar[(i<<6) + lane] = f2b(p[i]*inv);
}

// ---------------- host ----------------
extern "C" void kernel_launch(void* const* d_in, const int* in_sizes, int n_in,
                              void* d_out, int out_size, void* d_ws, size_t ws_size,
                              hipStream_t stream) {
  (void)in_sizes; (void)n_in; (void)out_size; (void)ws_size;
  const int*   trg  = (const int*)d_in[0];
  const int*   tlen = (const int*)d_in[1];
  const float* enc  = (const float*)d_in[2];
  const float* h0   = (const float*)d_in[3];
  const float* c0   = (const float*)d_in[4];
  const float* emb  = (const float*)d_in[5];
  const float* wih0 = (const float*)d_in[6];
  const float* wih1 = (const float*)d_in[7];
  const float* whh  = (const float*)d_in[8];
  const float* bih  = (const float*)d_in[9];
  const float* bhh  = (const float*)d_in[10];
  const float* watt = (const float*)d_in[11];
  const float* batt = (const float*)d_in[12];
  const float* wfc  = (const float*)d_in[13];
  const float* bfc  = (const float*)d_in[14];
  float* out = (float*)d_out;

  char* ws = (char*)d_ws;
  size_t off = 0;
  auto alloc = [&](size_t bytes)->char* {
    char* p = ws + off; off += (bytes + 255) & ~(size_t)255; return p;
  };
  unsigned int*   BAR   = (unsigned int*)  alloc(1024);    // flag lines
  float*          XG1   = (float*)         alloc(8ll*2*16*512*4*4);   // xg ring
  unsigned short* XEMB  = (unsigned short*)alloc(8192ll*512*2);
  unsigned short* WI0B  = (unsigned short*)alloc(4096ll*512*2);
  unsigned short* WFCB  = (unsigned short*)alloc(1000ll*1024*2);
  unsigned short* WATTB = (unsigned short*)alloc(512ll*512*2);
  unsigned short* ENCB  = (unsigned short*)alloc(8192ll*512*2);
  unsigned short* ENCT  = (unsigned short*)alloc(8192ll*512*2);
  float*          BSUM  = (float*)         alloc(8192*4);
  unsigned short* HST0  = (unsigned short*)alloc(32768*2);
  unsigned short* HST1  = (unsigned short*)alloc(32768*2);
  unsigned short* XG    = (unsigned short*)alloc(8192ll*4096*2);
  unsigned short* HCAT  = (unsigned short*)alloc(8192ll*1024*2);
  float*          HCATF = (float*)         alloc(8192ll*1024*4);
  float*          SCORE = (float*)         alloc(8192ll*512*4);   // enc_proj staging, then scores
  unsigned short* ATT   = (unsigned short*)alloc(8192ll*512*2);
  unsigned short* DCTX  = (unsigned short*)alloc(8192ll*1024*2);
  // DEC3/ENC3 alias XG (dead after k_recur): [8192][1536] each
  unsigned short* DEC3  = XG;
  unsigned short* ENC3  = XG + 8192ll*1536;

  auto cdiv = [](long a, long b){ return (int)((a + b - 1) / b); };

  // ---- prep ----
  k_cast<<<cdiv(2097152,256),256,0,stream>>>(wih0, WI0B, 2097152);
  k_cast<<<cdiv(1024000,256),256,0,stream>>>(wfc,  WFCB, 1024000);
  k_cast<<<cdiv(262144,256),256,0,stream>>>(watt, WATTB, 262144);
  k_cast<<<cdiv(4194304,256),256,0,stream>>>(enc,  ENCB, 4194304);
  k_transpose_enc<<<cdiv(4194304,256),256,0,stream>>>(enc, ENCT);
  k_gather<<<cdiv(4194304,256),256,0,stream>>>(trg, emb, XEMB);
  k_bsum<<<cdiv(8192,256),256,0,stream>>>(bih, bhh, BSUM);
  k_init<<<cdiv(32768,256),256,0,stream>>>(h0, HST0, HST1, BAR);

  // ---- enc_proj = enc @ W_att^T + b_att (f32) ----
  k_gemm<1><<<dim3(64,4,1),256,0,stream>>>(ENCB,512,0, WATTB,512,0, (void*)SCORE,512,0, batt, 8192,512,512, nullptr);

  // ---- X0 = Xemb @ W_ih0^T + (b_ih+b_hh)[0]  -> XG bf16 ----
  k_gemm<0><<<dim3(64,32,1),256,0,stream>>>(XEMB,512,0, WI0B,512,0, (void*)XG,4096,0, BSUM, 8192,4096,512, nullptr);

  // ---- fused pipelined 2-layer recurrence (producer/consumer blocks) ----
  k_recur<<<192,256,0,stream>>>(whh, wih1, XG, c0, BSUM, HST0, HST1, HCAT, HCATF, XG1, BAR);

  // ---- ENC3 (hi|lo|hi) from enc_proj; DEC3 (hi|hi|lo) + DCTX dec half ----
  k_split<<<cdiv(4194304,256),256,0,stream>>>(SCORE, ENC3, 4194304);
  k_decsplit<<<cdiv(4194304,256),256,0,stream>>>(HCATF, DCTX, DEC3);

  // ---- score: single K=1536 compensated GEMM (batched z=b) ----
  k_gemm<1><<<dim3(4,4,16),256,0,stream>>>(DEC3,24576,1536, ENC3,1536,786432, (void*)SCORE,512,262144, nullptr, 512,512,1536, nullptr);

  // ---- masked softmax -> ATT bf16 ----
  k_softmax<<<2048,256,0,stream>>>(SCORE, tlen, ATT);

  // ---- ctx[b,t,h] = att @ enc  -> DCTX[:, 512:] bf16 (batched) ----
  k_gemm<0><<<dim3(4,4,16),256,0,stream>>>(ATT,512,262144, ENCT,512,262144, (void*)(DCTX+512),16384,1024, nullptr, 512,512,512, nullptr);

  // ---- out = [dec,ctx] @ W_fc^T + b_fc, masked by trg_len ----
  k_gemm<2><<<dim3(64,8,1),256,0,stream>>>(DCTX,1024,0, WFCB,1024,0, (void*)out,1000,0, bfc, 8192,1000,1024, tlen);
}

// Round 15
// 1844.616 us; speedup vs baseline: 1.5755x; 1.0506x over previous
//
#include <hip/hip_runtime.h>
#include <cstdint>
#include <cstddef>

typedef __attribute__((ext_vector_type(8))) short short8;
typedef __attribute__((ext_vector_type(4))) float f32x4;
typedef __attribute__((ext_vector_type(4))) unsigned int uint4v;

#define DEV static __device__ __forceinline__

DEV float b2f(unsigned short u){ union{unsigned int i; float f;} v; v.i = ((unsigned int)u)<<16; return v.f; }
DEV unsigned short f2b(float f){
  union{float f; unsigned int i;} v; v.f = f;
  unsigned int u = v.i;
  unsigned int r = (u + 0x7fffu + ((u>>16)&1u)) >> 16;
  return (unsigned short)r;
}
DEV float sigm(float x){ return 1.0f/(1.0f + __expf(-x)); }
DEV float tanhfast(float x){ return 1.0f - 2.0f/(1.0f + __expf(2.0f*x)); }

// device-coherent (bypass L1/L2, complete at IF$) 16B load
DEV uint4v ld_sc_b128(const unsigned short* p){
  uint4v d;
  asm volatile("global_load_dwordx4 %0, %1, off sc0 sc1" : "=v"(d) : "v"(p) : "memory");
  return d;
}
// f32 row -> bf16x8 fragment
DEV short8 ldw8(const float* p){
  short8 w;
  #pragma unroll
  for (int e = 0; e < 8; ++e) w[e] = (short)f2b(p[e]);
  return w;
}

// ---------------- prep kernels ----------------
__global__ __launch_bounds__(256) void k_cast(const float* __restrict__ s, unsigned short* __restrict__ d, int n){
  int i = blockIdx.x*256 + threadIdx.x;
  if (i < n) d[i] = f2b(s[i]);
}
__global__ __launch_bounds__(256) void k_transpose_enc(const float* __restrict__ enc, unsigned short* __restrict__ encT){
  int i = blockIdx.x*256 + threadIdx.x;   // over 16*512*512, out index [b][h][s]
  if (i >= 16*512*512) return;
  int b = i >> 18, r = i & 262143, h = r >> 9, s = r & 511;
  encT[i] = f2b(enc[(b<<18) + (s<<9) + h]);
}
__global__ __launch_bounds__(256) void k_gather(const int* __restrict__ trg, const float* __restrict__ emb, unsigned short* __restrict__ X){
  int i = blockIdx.x*256 + threadIdx.x;   // over 8192*512, row = t*16+b
  if (i >= 8192*512) return;
  int r = i >> 9, e = i & 511;
  int t = r >> 4, b = r & 15;
  int tok = trg[(b<<9) + t];
  X[i] = f2b(emb[((size_t)tok<<9) + e]);
}
__global__ __launch_bounds__(256) void k_bsum(const float* __restrict__ bi, const float* __restrict__ bh, float* __restrict__ o){
  int i = blockIdx.x*256 + threadIdx.x;
  if (i < 8192) o[i] = bi[i] + bh[i];
}
__global__ __launch_bounds__(256) void k_init(const float* __restrict__ h0, unsigned short* __restrict__ Hst0,
                                              unsigned short* __restrict__ Hst1, unsigned int* __restrict__ bar){
  int i = blockIdx.x*256 + threadIdx.x;
  if (i < 256) bar[i] = 0;            // flags: l0 d0/d1 @0/32, l1 d0/d1 @64/96
  if (i < 16384) {                    // buf0 region: [dir][b][k] ; h0 flat [l*2+dir][b][k]
    Hst0[i] = f2b(h0[i]);             // layer 0: dirs 0,1
    Hst1[i] = f2b(h0[16384 + i]);     // layer 1: dirs 2,3
  }
}
// enc_proj f32 -> ENC3 [b*512+s][1536] = [hi | lo | hi]
__global__ __launch_bounds__(256) void k_split(const float* __restrict__ S, unsigned short* __restrict__ E3, int n){
  int i = blockIdx.x*256 + threadIdx.x;
  if (i >= n) return;
  int r = i >> 9, j = i & 511;
  float f = S[i];
  unsigned short hi = f2b(f);
  unsigned short lo = f2b(f - b2f(hi));
  size_t base = (size_t)r * 1536 + j;
  E3[base] = hi;
  E3[base + 512] = lo;
  E3[base + 1024] = hi;
}
// dec = hf+hb -> DCTX[:, :512] bf16 ; DEC3 [t*16+b][1536] = [hi | hi | lo]
__global__ __launch_bounds__(256) void k_decsplit(const float* __restrict__ HF, unsigned short* __restrict__ DCTX,
                                                  unsigned short* __restrict__ D3){
  int i = blockIdx.x*256 + threadIdx.x;  // 8192*512
  if (i >= 8192*512) return;
  int r = i >> 9, j = i & 511;
  float d = HF[((size_t)r<<10) + j] + HF[((size_t)r<<10) + 512 + j];
  unsigned short hi = f2b(d);
  unsigned short lo = f2b(d - b2f(hi));
  DCTX[((size_t)r<<10) + j] = hi;
  size_t base = (size_t)r * 1536 + j;
  D3[base] = hi;
  D3[base + 512] = hi;
  D3[base + 1024] = lo;
}

// ---------------- generic bf16 MFMA GEMM: C = A[M,K] @ W[N,K]^T (+bias) ----------------
// MODE: 0 = store bf16, 1 = store f32 (+bias), 2 = FC epilogue (mask+remap)
template<int MODE>
__global__ __launch_bounds__(256) void k_gemm(
    const unsigned short* __restrict__ A, long lda, long sA,
    const unsigned short* __restrict__ W, long ldw, long sW,
    void* __restrict__ C, long ldc, long sC,
    const float* __restrict__ bias,
    int M, int N, int K,
    const int* __restrict__ tlen)
{
  __shared__ short8 AsV[128*5];   // 128 rows x 32 bf16, padded stride 5x short8 (conflict-spread)
  __shared__ short8 WsV[128*5];
  const int bz = blockIdx.z;
  const unsigned short* Ab = A + (size_t)bz * sA;
  const unsigned short* Wb = W + (size_t)bz * sW;
  const int m0 = blockIdx.x << 7, n0 = blockIdx.y << 7;
  const int tid = threadIdx.x;
  const int wave = tid >> 6, lane = tid & 63;
  const int ln = lane & 15, kq = lane >> 4;
  const int wm = wave >> 1, wn = wave & 1;
  const int ar0 = tid >> 2, ac0 = (tid & 3) << 3;
  const int ar1 = ar0 + 64;
  const short8 z8 = {0,0,0,0,0,0,0,0};

  f32x4 acc[4][4];
  #pragma unroll
  for (int i = 0; i < 4; ++i)
    #pragma unroll
    for (int j = 0; j < 4; ++j) { f32x4 z = {0.f,0.f,0.f,0.f}; acc[i][j] = z; }

  for (int k0 = 0; k0 < K; k0 += 32) {
    short8 a0 = *(const short8*)(Ab + (size_t)(m0+ar0)*lda + k0 + ac0);
    short8 a1 = *(const short8*)(Ab + (size_t)(m0+ar1)*lda + k0 + ac0);
    short8 w0 = z8, w1 = z8;
    if (MODE != 2 || (n0+ar0) < N) w0 = *(const short8*)(Wb + (size_t)(n0+ar0)*ldw + k0 + ac0);
    if (MODE != 2 || (n0+ar1) < N) w1 = *(const short8*)(Wb + (size_t)(n0+ar1)*ldw + k0 + ac0);
    __syncthreads();
    AsV[ar0*5 + (ac0>>3)] = a0;
    AsV[ar1*5 + (ac0>>3)] = a1;
    WsV[ar0*5 + (ac0>>3)] = w0;
    WsV[ar1*5 + (ac0>>3)] = w1;
    __syncthreads();
    short8 af[4], wf[4];
    #pragma unroll
    for (int i = 0; i < 4; ++i) af[i] = AsV[((wm<<6) + (i<<4) + ln)*5 + kq];
    #pragma unroll
    for (int i = 0; i < 4; ++i) wf[i] = WsV[((wn<<6) + (i<<4) + ln)*5 + kq];
    #pragma unroll
    for (int i = 0; i < 4; ++i)
      #pragma unroll
      for (int j = 0; j < 4; ++j)
        acc[i][j] = __builtin_amdgcn_mfma_f32_16x16x32_bf16(af[i], wf[j], acc[i][j], 0, 0, 0);
  }
  #pragma unroll
  for (int j = 0; j < 4; ++j) {
    const int n = n0 + (wn<<6) + (j<<4) + ln;
    float bi = 0.f;
    if (MODE == 0 || MODE == 1) { if (bias) bi = bias[n]; }
    if (MODE == 2) { if (n < N) bi = bias[n]; }
    #pragma unroll
    for (int i = 0; i < 4; ++i) {
      #pragma unroll
      for (int r = 0; r < 4; ++r) {
        const int m = m0 + (wm<<6) + (i<<4) + (kq<<2) + r;
        float v = acc[i][j][r] + bi;
        if (MODE == 0) ((unsigned short*)C)[(size_t)bz*sC + (size_t)m*ldc + n] = f2b(v);
        else if (MODE == 1) ((float*)C)[(size_t)bz*sC + (size_t)m*ldc + n] = v;
        else {
          if (n < N) {
            int tt = m >> 4, bb = m & 15;
            ((float*)C)[((size_t)((bb<<9) + tt))*1000 + n] = (tt < tlen[bb]) ? v : 0.0f;
          }
        }
      }
    }
  }
}

// ---------------- fused 2-layer persistent LSTM (pipelined, 128 blocks) ----------------
// blocks 0-63: layer 0. blocks 64-127: layer 1 with x-gates computed OFF the
// critical path: xacc(t+1) (32 MFMAs over h0cat(t+1)) is computed in the step-t
// tail, after the flag store, overlapping other blocks' arrivals. In-chain work
// per l1 step = poll -> 16KB h1 stage -> 16 MFMAs (seeded with xacc) -> cell ->
// store -> flag, structurally identical to l0.
__global__ __launch_bounds__(256, 1) void k_recur(
    const float* __restrict__ whh,            // [2 layer][2 dir][2048][512] f32
    const float* __restrict__ wih1,           // [2 dir][2048][1024] f32
    const unsigned short* __restrict__ Xg0,   // [8192][4096] bf16 (l0: x@Wih0^T + biases)
    const float* __restrict__ c0all,          // [4][16][512] f32
    const float* __restrict__ bsum,           // [8192] f32 (b_ih+b_hh)
    unsigned short* __restrict__ Hst0,        // [2 buf][2 dir][16][512] bf16
    unsigned short* __restrict__ Hst1,        // [2 buf][2 dir][16][512] bf16
    unsigned short* __restrict__ Hcat,        // [8192][1024] bf16 (l0 output)
    float* __restrict__ HcatF,                // [8192][1024] f32  (l1 output)
    unsigned int* __restrict__ flags)
{
  const int bid = blockIdx.x;
  const int dir = (bid >> 5) & 1;
  const int j0  = (bid & 31) << 4;
  const int tid = threadIdx.x;
  const int wave = tid >> 6, lane = tid & 63;
  const int ln = lane & 15, kq = lane >> 4;
  const int b_ = tid >> 4, jl = tid & 15;
  const int myfl = bid & 31, pollfl = lane & 31;

  __shared__ __align__(16) unsigned char h0sh[32768];   // l1: h0cat tile [16][1024]
  __shared__ __align__(16) unsigned char h1sh[16384];   // own-h tile [16][512]
  __shared__ float gsh[4][16][16];

  unsigned int* FL0d0 = flags;
  unsigned int* FL0d1 = flags + 32;

  if (bid < 64) {
    // ================= layer 0 =================
    unsigned int* FL = flags + (dir << 5);
    short8 wfrag[16];
    {
      const float* wb = whh + (((size_t)((dir<<11) + (wave<<9) + j0 + ln)) << 9) + (kq<<3);
      #pragma unroll
      for (int ks = 0; ks < 16; ++ks) wfrag[ks] = ldw8(wb + (ks<<5));
    }
    float c = c0all[(((size_t)((dir<<4) + b_)) << 9) + j0 + jl];

    size_t xr = ((size_t)b_ << 12) + (dir<<11) + j0 + jl;
    float xg0 = b2f(Xg0[xr]);
    float xg1 = b2f(Xg0[xr + 512]);
    float xg2 = b2f(Xg0[xr + 1024]);
    float xg3 = b2f(Xg0[xr + 1536]);

    for (int t = 0; t < 512; ++t) {
      const unsigned short* hbase = Hst0 + ((((t&1)<<1) + dir)<<13);
      uint4v st[4];
      #pragma unroll
      for (int cc = 0; cc < 4; ++cc)
        st[cc] = ld_sc_b128(hbase + (cc<<11) + (tid<<3));
      asm volatile("s_waitcnt vmcnt(0)" ::: "memory");
      #pragma unroll
      for (int cc = 0; cc < 4; ++cc) {
        int g = (cc<<8) + tid, row = g >> 6, slot = g & 63, ps = slot ^ row;
        *(uint4v*)(h1sh + row*1024 + (ps<<4)) = st[cc];
      }
      __syncthreads();

      f32x4 acc0 = {0.f,0.f,0.f,0.f}, acc1 = {0.f,0.f,0.f,0.f};
      #pragma unroll
      for (int ks = 0; ks < 16; ks += 2) {
        short8 a0 = *(const short8*)(h1sh + ln*1024 + ((((ks<<2)+kq) ^ ln)<<4));
        short8 a1 = *(const short8*)(h1sh + ln*1024 + (((((ks+1)<<2)+kq) ^ ln)<<4));
        acc0 = __builtin_amdgcn_mfma_f32_16x16x32_bf16(a0, wfrag[ks],   acc0, 0, 0, 0);
        acc1 = __builtin_amdgcn_mfma_f32_16x16x32_bf16(a1, wfrag[ks+1], acc1, 0, 0, 0);
      }
      f32x4 acc = acc0 + acc1;
      #pragma unroll
      for (int r = 0; r < 4; ++r)
        gsh[wave][(kq<<2)+r][ln] = acc[r];
      __syncthreads();

      float gi = gsh[0][b_][jl] + xg0;
      float gf = gsh[1][b_][jl] + xg1;
      float gg = gsh[2][b_][jl] + xg2;
      float go = gsh[3][b_][jl] + xg3;
      float ii = sigm(gi), ff = sigm(gf);
      float g2 = tanhfast(gg), oo = sigm(go);
      c = ff*c + ii*g2;
      float h = oo * tanhfast(c);
      unsigned short h16 = f2b(h);

      // packed 8B sc stores: Hst0 next buf + Hcat (both published by the flag)
      unsigned int hu = (unsigned int)h16;
      unsigned int hv1 = __shfl_down(hu, 1);
      unsigned int hv2 = __shfl_down(hu, 2);
      unsigned int hv3 = __shfl_down(hu, 3);
      if (!(lane & 3)) {
        unsigned long long hq = (unsigned long long)(hu | (hv1 << 16))
                              | ((unsigned long long)(hv2 | (hv3 << 16)) << 32);
        unsigned short* dst = Hst0 + (((((t+1)&1)<<1) + dir)<<13) + (b_<<9) + j0 + jl;
        __hip_atomic_store((unsigned long long*)dst, hq, __ATOMIC_RELAXED, __HIP_MEMORY_SCOPE_AGENT);
        unsigned short* dc = Hcat + (((size_t)((t<<4) + b_))<<10) + (dir<<9) + j0 + jl;
        __hip_atomic_store((unsigned long long*)dc, hq, __ATOMIC_RELAXED, __HIP_MEMORY_SCOPE_AGENT);
      }

      // prefetch Xg for t+1 (plain cached; hides under the barrier)
      if (t < 511) {
        xr = (((size_t)(((t+1)<<4) + b_)) << 12) + (dir<<11) + j0 + jl;
        xg0 = b2f(Xg0[xr]);
        xg1 = b2f(Xg0[xr + 512]);
        xg2 = b2f(Xg0[xr + 1024]);
        xg3 = b2f(Xg0[xr + 1536]);
      }

      __syncthreads();   // vmcnt(0): sc stores acked at IF$
      if (tid == 0)
        __hip_atomic_store(FL + myfl, (unsigned int)(t + 1), __ATOMIC_RELAXED, __HIP_MEMORY_SCOPE_AGENT);
      if (t == 511) break;

      if (wave == 0) {
        const unsigned int tgt = (unsigned int)(t + 1);
        while (!__all((int)(__hip_atomic_load(FL + pollfl, __ATOMIC_RELAXED, __HIP_MEMORY_SCOPE_AGENT) >= tgt)))
          __builtin_amdgcn_s_sleep(1);
      }
      __syncthreads();
    }
  } else {
    // ================= layer 1 (x-gates off the critical path) =================
    unsigned int* FL = flags + 64 + (dir << 5);
    short8 whf[16];
    {
      const float* wb = whh + 2097152 + (((size_t)((dir<<11) + (wave<<9) + j0 + ln)) << 9) + (kq<<3);
      #pragma unroll
      for (int ks = 0; ks < 16; ++ks) whf[ks] = ldw8(wb + (ks<<5));
    }
    short8 wxf[32];
    {
      const float* xb = wih1 + (((size_t)((dir<<11) + (wave<<9) + j0 + ln)) << 10) + (kq<<3);
      #pragma unroll
      for (int ks = 0; ks < 32; ++ks) wxf[ks] = ldw8(xb + (ks<<5));
    }
    float c = c0all[16384 + (((size_t)((dir<<4) + b_)) << 9) + j0 + jl];
    float bs0 = bsum[4096 + (dir<<11) + 0*512 + j0 + jl];
    float bs1 = bsum[4096 + (dir<<11) + 1*512 + j0 + jl];
    float bs2 = bsum[4096 + (dir<<11) + 2*512 + j0 + jl];
    float bs3 = bsum[4096 + (dir<<11) + 3*512 + j0 + jl];

    // prologue: wait l0 (both dirs) >= 2 -> h0cat(0), h0cat(1) proven ready
    if (wave == 0) {
      const unsigned int* fp = (lane < 32) ? (FL0d0 + lane) : (FL0d1 + (lane - 32));
      while (!__all((int)(__hip_atomic_load(fp, __ATOMIC_RELAXED, __HIP_MEMORY_SCOPE_AGENT) >= 2u)))
        __builtin_amdgcn_s_sleep(1);
    }
    __syncthreads();

    uint4v sxr[8];   // h0cat register prefetch buffer
    #pragma unroll
    for (int cc = 0; cc < 8; ++cc) {
      int g = (cc<<8) + tid, row = g >> 7, slot = g & 127;
      sxr[cc] = ld_sc_b128(Hcat + (row<<10) + (slot<<3));
    }
    asm volatile("s_waitcnt vmcnt(0)" ::: "memory");
    #pragma unroll
    for (int cc = 0; cc < 8; ++cc) {
      int g = (cc<<8) + tid, row = g >> 7, slot = g & 127, ps = slot ^ row;
      *(uint4v*)(h0sh + row*2048 + (ps<<4)) = sxr[cc];
    }
    __syncthreads();
    // xacc(0)
    f32x4 xacc;
    {
      f32x4 xa = {0.f,0.f,0.f,0.f}, xb2 = {0.f,0.f,0.f,0.f};
      #pragma unroll
      for (int ks = 0; ks < 32; ks += 2) {
        short8 a0 = *(const short8*)(h0sh + ln*2048 + ((((ks<<2)+kq) ^ ln)<<4));
        short8 a1 = *(const short8*)(h0sh + ln*2048 + (((((ks+1)<<2)+kq) ^ ln)<<4));
        xa  = __builtin_amdgcn_mfma_f32_16x16x32_bf16(a0, wxf[ks],   xa, 0, 0, 0);
        xb2 = __builtin_amdgcn_mfma_f32_16x16x32_bf16(a1, wxf[ks+1], xb2, 0, 0, 0);
      }
      xacc = xa + xb2;
    }
    // issue sxr(1) (proven by l0 >= 2)
    #pragma unroll
    for (int cc = 0; cc < 8; ++cc) {
      int g = (cc<<8) + tid, row = g >> 7, slot = g & 127;
      sxr[cc] = ld_sc_b128(Hcat + 16384 + (row<<10) + (slot<<3));
    }

    for (int t = 0; t < 512; ++t) {
      // (A) polls: own h1(t) ready; l0 ahead for the NEXT sxr issue
      if (wave == 0) {
        const unsigned int tgt = (unsigned int)t;
        if (t > 0)
          while (!__all((int)(__hip_atomic_load(FL + pollfl, __ATOMIC_RELAXED, __HIP_MEMORY_SCOPE_AGENT) >= tgt)))
            __builtin_amdgcn_s_sleep(1);
      } else if (wave == 1) {
        const unsigned int tgt = (t + 3 < 512) ? (unsigned int)(t + 3) : 512u;
        const unsigned int* fp = (lane < 32) ? (FL0d0 + lane) : (FL0d1 + (lane - 32));
        while (!__all((int)(__hip_atomic_load(fp, __ATOMIC_RELAXED, __HIP_MEMORY_SCOPE_AGENT) >= tgt)))
          __builtin_amdgcn_s_sleep(1);
      }
      __syncthreads();   // (D)

      // stage h1(t): 16KB sc — the only barrier-dependent load latency
      const unsigned short* h1base = Hst1 + ((((t&1)<<1) + dir)<<13);
      uint4v sh[4];
      #pragma unroll
      for (int cc = 0; cc < 4; ++cc)
        sh[cc] = ld_sc_b128(h1base + (cc<<11) + (tid<<3));
      asm volatile("s_waitcnt vmcnt(0)" ::: "memory");   // h1 ready (and sxr(t+1) ready)
      #pragma unroll
      for (int cc = 0; cc < 4; ++cc) {
        int g = (cc<<8) + tid, row = g >> 6, slot = g & 63, ps = slot ^ row;
        *(uint4v*)(h1sh + row*1024 + (ps<<4)) = sh[cc];
      }
      __syncthreads();   // (Async)

      f32x4 acc0 = xacc, acc1 = {0.f,0.f,0.f,0.f};
      #pragma unroll
      for (int ks = 0; ks < 16; ks += 2) {
        short8 a0 = *(const short8*)(h1sh + ln*1024 + ((((ks<<2)+kq) ^ ln)<<4));
        short8 a1 = *(const short8*)(h1sh + ln*1024 + (((((ks+1)<<2)+kq) ^ ln)<<4));
        acc0 = __builtin_amdgcn_mfma_f32_16x16x32_bf16(a0, whf[ks],   acc0, 0, 0, 0);
        acc1 = __builtin_amdgcn_mfma_f32_16x16x32_bf16(a1, whf[ks+1], acc1, 0, 0, 0);
      }
      f32x4 acc = acc0 + acc1;
      #pragma unroll
      for (int r = 0; r < 4; ++r)
        gsh[wave][(kq<<2)+r][ln] = acc[r];
      __syncthreads();   // (B)

      float gi = gsh[0][b_][jl] + bs0;
      float gf = gsh[1][b_][jl] + bs1;
      float gg = gsh[2][b_][jl] + bs2;
      float go = gsh[3][b_][jl] + bs3;
      float ii = sigm(gi), ff = sigm(gf);
      float g2 = tanhfast(gg), oo = sigm(go);
      c = ff*c + ii*g2;
      float h = oo * tanhfast(c);
      unsigned short h16 = f2b(h);

      // packed 8B sc store: Hst1 next buf
      unsigned int hu = (unsigned int)h16;
      unsigned int hv1 = __shfl_down(hu, 1);
      unsigned int hv2 = __shfl_down(hu, 2);
      unsigned int hv3 = __shfl_down(hu, 3);
      if (!(lane & 3)) {
        unsigned long long hq = (unsigned long long)(hu | (hv1 << 16))
                              | ((unsigned long long)(hv2 | (hv3 << 16)) << 32);
        unsigned short* dst = Hst1 + (((((t+1)&1)<<1) + dir)<<13) + (b_<<9) + j0 + jl;
        __hip_atomic_store((unsigned long long*)dst, hq, __ATOMIC_RELAXED, __HIP_MEMORY_SCOPE_AGENT);
      }

      __syncthreads();   // (C) vmcnt(0): sc store acked
      if (tid == 0)
        __hip_atomic_store(FL + myfl, (unsigned int)(t + 1), __ATOMIC_RELAXED, __HIP_MEMORY_SCOPE_AGENT);

      // streaming fp32 output; drains off-path
      __builtin_nontemporal_store(h, HcatF + (((size_t)((t<<4) + b_))<<10) + (dir<<9) + j0 + jl);

      if (t == 511) break;

      // ---- tail (off critical path): x-work for step t+1 ----
      // copy sxr(t+1) -> h0sh (last h0sh reads were in the previous tail, fenced by D/A/B/C)
      #pragma unroll
      for (int cc = 0; cc < 8; ++cc) {
        int g = (cc<<8) + tid, row = g >> 7, slot = g & 127, ps = slot ^ row;
        *(uint4v*)(h0sh + row*2048 + (ps<<4)) = sxr[cc];
      }
      __syncthreads();   // (E)
      {
        f32x4 xa = {0.f,0.f,0.f,0.f}, xb2 = {0.f,0.f,0.f,0.f};
        #pragma unroll
        for (int ks = 0; ks < 32; ks += 2) {
          short8 a0 = *(const short8*)(h0sh + ln*2048 + ((((ks<<2)+kq) ^ ln)<<4));
          short8 a1 = *(const short8*)(h0sh + ln*2048 + (((((ks+1)<<2)+kq) ^ ln)<<4));
          xa  = __builtin_amdgcn_mfma_f32_16x16x32_bf16(a0, wxf[ks],   xa, 0, 0, 0);
          xb2 = __builtin_amdgcn_mfma_f32_16x16x32_bf16(a1, wxf[ks+1], xb2, 0, 0, 0);
        }
        xacc = xa + xb2;
      }
      // issue sxr(t+2) (proven by this iteration's wave-1 poll: l0 >= t+3)
      if (t < 510) {
        const unsigned short* hb0 = Hcat + (((size_t)(t+2)) << 14);
        #pragma unroll
        for (int cc = 0; cc < 8; ++cc) {
          int g = (cc<<8) + tid, row = g >> 7, slot = g & 127;
          sxr[cc] = ld_sc_b128(hb0 + (row<<10) + (slot<<3));
        }
      }
    }
  }
}

// ---------------- softmax over masked scores -> bf16 attention ----------------
__global__ __launch_bounds__(256) void k_softmax(const float* __restrict__ score, const int* __restrict__ tlen,
                                                 unsigned short* __restrict__ att){
  int row = (blockIdx.x<<2) + (threadIdx.x>>6);   // row = b*512 + t
  int lane = threadIdx.x & 63;
  int b = row >> 9;
  int len = tlen[b];
  const float* sr = score + ((size_t)row<<9);
  float v[8]; float m = -3.0e38f;
  #pragma unroll
  for (int i = 0; i < 8; ++i) {
    int s = (i<<6) + lane;
    float x = sr[s];
    v[i] = (s < len) ? x : -1.0e30f;
    m = fmaxf(m, v[i]);
  }
  #pragma unroll
  for (int off = 32; off; off >>= 1) m = fmaxf(m, __shfl_xor(m, off));
  float sum = 0.f; float p[8];
  #pragma unroll
  for (int i = 0; i < 8; ++i) { p[i] = __expf(v[i] - m); sum += p[i]; }
  #pragma unroll
  for (int off = 32; off; off >>= 1) sum += __shfl_xor(sum, off);
  float inv = 1.0f / sum;
  unsigned short* ar = att + ((size_t)row<<9);
  #pragma unroll
  for (int i = 0; i < 8; ++i) ar[(i<<6) + lane] = f2b(p[i]*inv);
}

// ---------------- host ----------------
extern "C" void kernel_launch(void* const* d_in, const int* in_sizes, int n_in,
                              void* d_out, int out_size, void* d_ws, size_t ws_size,
                              hipStream_t stream) {
  (void)in_sizes; (void)n_in; (void)out_size; (void)ws_size;
  const int*   trg  = (const int*)d_in[0];
  const int*   tlen = (const int*)d_in[1];
  const float* enc  = (const float*)d_in[2];
  const float* h0   = (const float*)d_in[3];
  const float* c0   = (const float*)d_in[4];
  const float* emb  = (const float*)d_in[5];
  const float* wih0 = (const float*)d_in[6];
  const float* wih1 = (const float*)d_in[7];
  const float* whh  = (const float*)d_in[8];
  const float* bih  = (const float*)d_in[9];
  const float* bhh  = (const float*)d_in[10];
  const float* watt = (const float*)d_in[11];
  const float* batt = (const float*)d_in[12];
  const float* wfc  = (const float*)d_in[13];
  const float* bfc  = (const float*)d_in[14];
  float* out = (float*)d_out;

  char* ws = (char*)d_ws;
  size_t off = 0;
  auto alloc = [&](size_t bytes)->char* {
    char* p = ws + off; off += (bytes + 255) & ~(size_t)255; return p;
  };
  unsigned int*   BAR   = (unsigned int*)  alloc(1024);    // flag lines
  unsigned short* XEMB  = (unsigned short*)alloc(8192ll*512*2);
  unsigned short* WI0B  = (unsigned short*)alloc(4096ll*512*2);
  unsigned short* WFCB  = (unsigned short*)alloc(1000ll*1024*2);
  unsigned short* WATTB = (unsigned short*)alloc(512ll*512*2);
  unsigned short* ENCB  = (unsigned short*)alloc(8192ll*512*2);
  unsigned short* ENCT  = (unsigned short*)alloc(8192ll*512*2);
  float*          BSUM  = (float*)         alloc(8192*4);
  unsigned short* HST0  = (unsigned short*)alloc(32768*2);
  unsigned short* HST1  = (unsigned short*)alloc(32768*2);
  unsigned short* XG    = (unsigned short*)alloc(8192ll*4096*2);
  unsigned short* HCAT  = (unsigned short*)alloc(8192ll*1024*2);
  float*          HCATF = (float*)         alloc(8192ll*1024*4);
  float*          SCORE = (float*)         alloc(8192ll*512*4);   // enc_proj staging, then scores
  unsigned short* ATT   = (unsigned short*)alloc(8192ll*512*2);
  unsigned short* DCTX  = (unsigned short*)alloc(8192ll*1024*2);
  // DEC3/ENC3 alias XG (dead after k_recur): [8192][1536] each
  unsigned short* DEC3  = XG;
  unsigned short* ENC3  = XG + 8192ll*1536;

  auto cdiv = [](long a, long b){ return (int)((a + b - 1) / b); };

  // ---- prep ----
  k_cast<<<cdiv(2097152,256),256,0,stream>>>(wih0, WI0B, 2097152);
  k_cast<<<cdiv(1024000,256),256,0,stream>>>(wfc,  WFCB, 1024000);
  k_cast<<<cdiv(262144,256),256,0,stream>>>(watt, WATTB, 262144);
  k_cast<<<cdiv(4194304,256),256,0,stream>>>(enc,  ENCB, 4194304);
  k_transpose_enc<<<cdiv(4194304,256),256,0,stream>>>(enc, ENCT);
  k_gather<<<cdiv(4194304,256),256,0,stream>>>(trg, emb, XEMB);
  k_bsum<<<cdiv(8192,256),256,0,stream>>>(bih, bhh, BSUM);
  k_init<<<cdiv(32768,256),256,0,stream>>>(h0, HST0, HST1, BAR);

  // ---- enc_proj = enc @ W_att^T + b_att (f32) ----
  k_gemm<1><<<dim3(64,4,1),256,0,stream>>>(ENCB,512,0, WATTB,512,0, (void*)SCORE,512,0, batt, 8192,512,512, nullptr);

  // ---- X0 = Xemb @ W_ih0^T + (b_ih+b_hh)[0]  -> XG bf16 ----
  k_gemm<0><<<dim3(64,32,1),256,0,stream>>>(XEMB,512,0, WI0B,512,0, (void*)XG,4096,0, BSUM, 8192,4096,512, nullptr);

  // ---- fused pipelined 2-layer recurrence ----
  k_recur<<<128,256,0,stream>>>(whh, wih1, XG, c0, BSUM, HST0, HST1, HCAT, HCATF, BAR);

  // ---- ENC3 (hi|lo|hi) from enc_proj; DEC3 (hi|hi|lo) + DCTX dec half ----
  k_split<<<cdiv(4194304,256),256,0,stream>>>(SCORE, ENC3, 4194304);
  k_decsplit<<<cdiv(4194304,256),256,0,stream>>>(HCATF, DCTX, DEC3);

  // ---- score: single K=1536 compensated GEMM (batched z=b) ----
  k_gemm<1><<<dim3(4,4,16),256,0,stream>>>(DEC3,24576,1536, ENC3,1536,786432, (void*)SCORE,512,262144, nullptr, 512,512,1536, nullptr);

  // ---- masked softmax -> ATT bf16 ----
  k_softmax<<<2048,256,0,stream>>>(SCORE, tlen, ATT);

  // ---- ctx[b,t,h] = att @ enc  -> DCTX[:, 512:] bf16 (batched) ----
  k_gemm<0><<<dim3(4,4,16),256,0,stream>>>(ATT,512,262144, ENCT,512,262144, (void*)(DCTX+512),16384,1024, nullptr, 512,512,512, nullptr);

  // ---- out = [dec,ctx] @ W_fc^T + b_fc, masked by trg_len ----
  k_gemm<2><<<dim3(64,8,1),256,0,stream>>>(DCTX,1024,0, WFCB,1024,0, (void*)out,1000,0, bfc, 8192,1000,1024, tlen);
}